// Round 2
// baseline (1305.243 us; speedup 1.0000x reference)
//
#include <hip/hip_runtime.h>
#include <math.h>

// ---------------- constants ----------------
#define NB    2
#define HH    128
#define WW2   128
#define NN    16384            // H*W
#define DIM_  192
#define HEADS_ 6
#define HD_   32
#define NT_   128
#define RD_   20
#define HID_  384
#define ROWS  32768            // B*N
#define HD_SCALE 0.17677669529663687f  // 1/sqrt(32)
#define LOG100   4.6051701859880914f
#define LOGNT    4.852030263919617f    // ln(128)

__device__ __forceinline__ float gelu_f(float v) {
  return 0.5f * v * (1.0f + erff(v * 0.7071067811865475f));
}

// window row (0..32767) -> global token row (b*16384+n), same map for gather & scatter
__device__ __forceinline__ int winmap_row(int r) {
  int b_ = r >> 8;
  int p  = r & 255;
  int b  = b_ >> 6;
  int win = b_ & 63;
  int y = ((win >> 3) << 4) + (p >> 4);
  int x = ((win & 7) << 4) + (p & 15);
  int n = (((y + 8) & 127) << 7) + ((x + 8) & 127);
  return (b << 14) + n;
}

// ---------------- LayerNorm over 192 (wave per row) ----------------
__global__ __launch_bounds__(256)
void ln_kernel(const float* __restrict__ in, const float* __restrict__ w,
               const float* __restrict__ bv, float* __restrict__ out, int nrows) {
  int wave = threadIdx.x >> 6, lane = threadIdx.x & 63;
  int row = blockIdx.x * 4 + wave;
  if (row >= nrows) return;
  const float* p = in + (size_t)row * DIM_;
  float v0 = p[lane], v1 = p[lane + 64], v2 = p[lane + 128];
  float s = v0 + v1 + v2;
  #pragma unroll
  for (int m = 32; m; m >>= 1) s += __shfl_xor(s, m, 64);
  float mu = s * (1.0f / 192.0f);
  float d0 = v0 - mu, d1 = v1 - mu, d2 = v2 - mu;
  float q = d0 * d0 + d1 * d1 + d2 * d2;
  #pragma unroll
  for (int m = 32; m; m >>= 1) q += __shfl_xor(q, m, 64);
  float rs = rsqrtf(q * (1.0f / 192.0f) + 1e-5f);
  float* o = out + (size_t)row * DIM_;
  o[lane]       = d0 * rs * w[lane]       + bv[lane];
  o[lane + 64]  = d1 * rs * w[lane + 64]  + bv[lane + 64];
  o[lane + 128] = d2 * rs * w[lane + 128] + bv[lane + 128];
}

// ---------------- generic tiled f32 GEMM: C = act(A@W + bias), optional scatter/add ----------------
// BM=BN=64, BK=32, 256 threads, 4x4 per thread.
// AT: A stored K-major (A[k*lda+m]); RMODE: 0 none, 1 winmap, 2 rowmap array.
template<bool AT, bool BIAS, bool DOGELU, int RMODE, bool ADD>
__global__ __launch_bounds__(256)
void gemm64(const float* __restrict__ A, const float* __restrict__ W,
            const float* __restrict__ bias, float* __restrict__ C,
            int M, int N, int K, int lda, const int* __restrict__ rowmap) {
  __shared__ float As[64][33];
  __shared__ float Bs[32][64];
  int tid = threadIdx.x;
  int tx = tid & 15, ty = tid >> 4;
  int m0 = blockIdx.y * 64, n0 = blockIdx.x * 64;
  float c[4][4] = {};
  for (int k0 = 0; k0 < K; k0 += 32) {
    if (!AT) {
      #pragma unroll
      for (int q = 0; q < 2; ++q) {
        int i = tid * 2 + q;
        int mr = i >> 3, kc = (i & 7) << 2;
        float4 v = *(const float4*)(A + (size_t)(m0 + mr) * lda + k0 + kc);
        As[mr][kc] = v.x; As[mr][kc + 1] = v.y; As[mr][kc + 2] = v.z; As[mr][kc + 3] = v.w;
      }
    } else {
      #pragma unroll
      for (int q = 0; q < 2; ++q) {
        int i = tid * 2 + q;
        int kc = i >> 4, mr = (i & 15) << 2;
        float4 v = *(const float4*)(A + (size_t)(k0 + kc) * lda + m0 + mr);
        As[mr][kc] = v.x; As[mr + 1][kc] = v.y; As[mr + 2][kc] = v.z; As[mr + 3][kc] = v.w;
      }
    }
    #pragma unroll
    for (int q = 0; q < 2; ++q) {
      int i = tid * 2 + q;
      int kc = i >> 4, nc = (i & 15) << 2;
      int col = n0 + nc;
      float4 v = make_float4(0.f, 0.f, 0.f, 0.f);
      if (col + 3 < N) {
        v = *(const float4*)(W + (size_t)(k0 + kc) * N + col);
      } else {
        float t[4] = {0.f, 0.f, 0.f, 0.f};
        #pragma unroll
        for (int e = 0; e < 4; ++e) if (col + e < N) t[e] = W[(size_t)(k0 + kc) * N + col + e];
        v = make_float4(t[0], t[1], t[2], t[3]);
      }
      *(float4*)&Bs[kc][nc] = v;
    }
    __syncthreads();
    #pragma unroll
    for (int kk = 0; kk < 32; ++kk) {
      float a0 = As[(ty << 2) + 0][kk];
      float a1 = As[(ty << 2) + 1][kk];
      float a2 = As[(ty << 2) + 2][kk];
      float a3 = As[(ty << 2) + 3][kk];
      float4 b = *(const float4*)&Bs[kk][tx << 2];
      c[0][0] += a0 * b.x; c[0][1] += a0 * b.y; c[0][2] += a0 * b.z; c[0][3] += a0 * b.w;
      c[1][0] += a1 * b.x; c[1][1] += a1 * b.y; c[1][2] += a1 * b.z; c[1][3] += a1 * b.w;
      c[2][0] += a2 * b.x; c[2][1] += a2 * b.y; c[2][2] += a2 * b.z; c[2][3] += a2 * b.w;
      c[3][0] += a3 * b.x; c[3][1] += a3 * b.y; c[3][2] += a3 * b.z; c[3][3] += a3 * b.w;
    }
    __syncthreads();
  }
  #pragma unroll
  for (int i = 0; i < 4; ++i) {
    int row = m0 + (ty << 2) + i;
    int drow;
    if (RMODE == 1) drow = winmap_row(row);
    else if (RMODE == 2) drow = rowmap[row];
    else drow = row;
    float* crow = C + (size_t)drow * N;
    #pragma unroll
    for (int j = 0; j < 4; ++j) {
      int col = n0 + (tx << 2) + j;
      if (col < N) {
        float v = c[i][j];
        if (BIAS) v += bias[col];
        if (DOGELU) v = gelu_f(v);
        if (ADD) crow[col] += v; else crow[col] = v;
      }
    }
  }
}

// ---------------- flash attention over 256x256, head-dim 32 ----------------
// WIN=true: shifted-window MSA (rpb + mask, scale=1/sqrt(32), rows via winmap)
// WIN=false: category MSA (scale=exp(min(logit_scale, ln100)), rows via sort_row)
template<bool WIN>
__global__ __launch_bounds__(256)
void attn_kernel(const float* __restrict__ qkv, const int* __restrict__ sort_row,
                 const float* __restrict__ rpb_table, const int* __restrict__ rpi,
                 const float* __restrict__ mask, const float* __restrict__ ls_ptr,
                 float* __restrict__ obuf) {
  __shared__ float Ks[256][32];
  __shared__ float Vs[256][32];
  int b_ = blockIdx.x, head = blockIdx.y;
  int tid = threadIdx.x;
  #pragma unroll
  for (int it = 0; it < 8; ++it) {
    int j = it * 32 + (tid >> 3);
    int q4 = tid & 7;
    int src = WIN ? winmap_row(b_ * 256 + j) : sort_row[b_ * 256 + j];
    const float4* rowp = (const float4*)(qkv + (size_t)src * 576);
    float4 kv = rowp[48 + head * 8 + q4];
    float4 vv = rowp[96 + head * 8 + q4];
    *(float4*)&Ks[j][q4 << 2] = kv;
    *(float4*)&Vs[j][q4 << 2] = vv;
  }
  int i = tid;
  int srcq = WIN ? winmap_row(b_ * 256 + i) : sort_row[b_ * 256 + i];
  float qr[32];
  {
    const float4* rowp = (const float4*)(qkv + (size_t)srcq * 576);
    #pragma unroll
    for (int q4 = 0; q4 < 8; ++q4) {
      float4 v = rowp[head * 8 + q4];
      qr[q4 * 4] = v.x; qr[q4 * 4 + 1] = v.y; qr[q4 * 4 + 2] = v.z; qr[q4 * 4 + 3] = v.w;
    }
  }
  float scale = WIN ? HD_SCALE : __expf(fminf(ls_ptr[0], LOG100));
  const float* mrow = WIN ? (mask + ((size_t)(b_ & 63)) * 65536 + (size_t)i * 256) : nullptr;
  const int*   rrow = WIN ? (rpi + (size_t)i * 256) : nullptr;
  __syncthreads();
  float m = -3.4e38f, l = 0.f, acc[32];
  #pragma unroll
  for (int d = 0; d < 32; ++d) acc[d] = 0.f;
  for (int j0 = 0; j0 < 256; j0 += 16) {
    float s[16];
    #pragma unroll
    for (int jj = 0; jj < 16; ++jj) {
      const float* kp = Ks[j0 + jj];
      float a = 0.f;
      #pragma unroll
      for (int d = 0; d < 32; ++d) a += qr[d] * kp[d];
      s[jj] = a * scale;
      if (WIN) s[jj] += rpb_table[rrow[j0 + jj] * HEADS_ + head] + mrow[j0 + jj];
    }
    float cm = s[0];
    #pragma unroll
    for (int jj = 1; jj < 16; ++jj) cm = fmaxf(cm, s[jj]);
    float mn = fmaxf(m, cm);
    float corr = __expf(m - mn);
    l *= corr;
    #pragma unroll
    for (int d = 0; d < 32; ++d) acc[d] *= corr;
    #pragma unroll
    for (int jj = 0; jj < 16; ++jj) {
      float p = __expf(s[jj] - mn);
      l += p;
      const float* vp = Vs[j0 + jj];
      #pragma unroll
      for (int d = 0; d < 32; ++d) acc[d] += p * vp[d];
    }
    m = mn;
  }
  float inv = 1.0f / l;
  float* op = obuf + ((size_t)(b_ * 256 + i)) * DIM_ + head * HD_;
  #pragma unroll
  for (int d4 = 0; d4 < 8; ++d4) {
    float4 v = make_float4(acc[d4 * 4] * inv, acc[d4 * 4 + 1] * inv,
                           acc[d4 * 4 + 2] * inv, acc[d4 * 4 + 3] * inv);
    *(float4*)(op + d4 * 4) = v;
  }
}

// ---------------- row L2-normalize, width 20 ----------------
__global__ __launch_bounds__(256)
void normrows20(float* __restrict__ p, int rows) {
  int r = blockIdx.x * 256 + threadIdx.x;
  if (r >= rows) return;
  float4* rp = (float4*)(p + (size_t)r * RD_);
  float4 v[5];
  float s = 0.f;
  #pragma unroll
  for (int e = 0; e < 5; ++e) {
    v[e] = rp[e];
    s += v[e].x * v[e].x + v[e].y * v[e].y + v[e].z * v[e].z + v[e].w * v[e].w;
  }
  float inv = 1.0f / fmaxf(sqrtf(s), 1e-12f);
  #pragma unroll
  for (int e = 0; e < 5; ++e) {
    v[e].x *= inv; v[e].y *= inv; v[e].z *= inv; v[e].w *= inv;
    rp[e] = v[e];
  }
}

// ---------------- sim logits (stored transposed) + row stats + argmax ----------------
__global__ __launch_bounds__(256)
void sim1_kernel(const float* __restrict__ qa, const float* __restrict__ ka,
                 const float* __restrict__ atd_scale, float* __restrict__ simT,
                 float* __restrict__ m_out, float* __restrict__ den_out, int* __restrict__ tk) {
  __shared__ float kas[NT_ * RD_];
  __shared__ float scl[NT_];
  int tid = threadIdx.x;
  int gi = blockIdx.x * 256 + tid;         // 0..32767
  int b = blockIdx.x >> 6;
  for (int idx = tid; idx < NT_ * RD_; idx += 256) kas[idx] = ka[b * NT_ * RD_ + idx];
  for (int t = tid; t < NT_; t += 256)
    scl[t] = 1.0f + fminf(fmaxf(atd_scale[t], 0.f), 1.f) * LOGNT;
  __syncthreads();
  float q[20];
  const float4* qp = (const float4*)(qa + (size_t)gi * RD_);
  #pragma unroll
  for (int e = 0; e < 5; ++e) {
    float4 v = qp[e];
    q[e * 4] = v.x; q[e * 4 + 1] = v.y; q[e * 4 + 2] = v.z; q[e * 4 + 3] = v.w;
  }
  int n = gi & (NN - 1);
  float m = -3.4e38f, l = 0.f;
  int am = 0;
  float* srow = simT + (size_t)b * NT_ * NN + n;
  for (int t = 0; t < NT_; ++t) {
    const float* kp = &kas[t * RD_];
    float d = 0.f;
    #pragma unroll
    for (int e = 0; e < 20; ++e) d += q[e] * kp[e];
    d *= scl[t];
    srow[(size_t)t * NN] = d;
    if (d > m) { l = l * __expf(m - d) + 1.0f; m = d; am = t; }
    else       { l += __expf(d - m); }
  }
  m_out[gi] = m; den_out[gi] = l; tk[gi] = am;
}

// ---------------- normalize logits -> probs (in place on simT) ----------------
__global__ __launch_bounds__(256)
void sim2_kernel(float* __restrict__ simT, const float* __restrict__ m_i,
                 const float* __restrict__ den_i) {
  size_t idx = (size_t)blockIdx.x * 256 + threadIdx.x;   // 4,194,304 total
  int b = (int)(idx >> 21);
  int n = (int)(idx & (NN - 1));
  int gi = (b << 14) + n;
  float r = simT[idx];
  simT[idx] = __expf(r - m_i[gi]) / den_i[gi];
}

// ---------------- counting sort (stable) ----------------
__global__ __launch_bounds__(256)
void hist_kernel(const int* __restrict__ tk, int* __restrict__ chist) {
  __shared__ int h[NT_];
  int tid = threadIdx.x, ch = blockIdx.x, b = blockIdx.y;
  if (tid < NT_) h[tid] = 0;
  __syncthreads();
  int bin = tk[b * NN + ch * 256 + tid];
  atomicAdd(&h[bin], 1);
  __syncthreads();
  if (tid < NT_) chist[(b * 64 + ch) * NT_ + tid] = h[tid];
}

__global__ __launch_bounds__(128)
void offsets_kernel(const int* __restrict__ chist, int* __restrict__ offs) {
  int b = blockIdx.x, bin = threadIdx.x;
  int total = 0;
  for (int ch = 0; ch < 64; ++ch) total += chist[(b * 64 + ch) * NT_ + bin];
  __shared__ int sc[NT_];
  sc[bin] = total;
  __syncthreads();
  int base = 0;
  for (int i = 0; i < bin; ++i) base += sc[i];
  int run = base;
  for (int ch = 0; ch < 64; ++ch) {
    offs[(b * 64 + ch) * NT_ + bin] = run;
    run += chist[(b * 64 + ch) * NT_ + bin];
  }
}

__global__ __launch_bounds__(256)
void scatter_kernel(const int* __restrict__ tk, const int* __restrict__ offs,
                    int* __restrict__ sort_row) {
  __shared__ int bins[256];
  int tid = threadIdx.x, ch = blockIdx.x, b = blockIdx.y;
  int i = ch * 256 + tid;
  int bin = tk[b * NN + i];
  bins[tid] = bin;
  __syncthreads();
  int rank = 0;
  for (int j = 0; j < tid; ++j) rank += (bins[j] == bin) ? 1 : 0;
  int pos = offs[(b * 64 + ch) * NT_ + bin] + rank;
  sort_row[b * NN + pos] = b * NN + i;
}

// ---------------- depthwise 5x5 conv + bias + gelu ----------------
__global__ __launch_bounds__(384)
void dwconv_kernel(const float* __restrict__ hdn, const float* __restrict__ wgt,
                   const float* __restrict__ bv, float* __restrict__ out) {
  int c = threadIdx.x;
  int xt = blockIdx.x, y = blockIdx.y, b = blockIdx.z;
  float wr[25];
  #pragma unroll
  for (int t = 0; t < 25; ++t) wr[t] = wgt[c * 25 + t];
  float bias = bv[c];
  int x0 = xt * 16;
  const float* base = hdn + (size_t)b * NN * HID_;
  float win[5][5];
  #pragma unroll
  for (int r = 0; r < 5; ++r) {
    int yy = y + r - 2;
    #pragma unroll
    for (int t = 0; t < 4; ++t) {
      int xx = x0 - 2 + t;
      win[r][t] = (yy >= 0 && yy < HH && xx >= 0 && xx < WW2)
                    ? base[((size_t)yy * WW2 + xx) * HID_ + c] : 0.f;
    }
  }
  for (int x = x0; x < x0 + 16; ++x) {
    int xx = x + 2;
    #pragma unroll
    for (int r = 0; r < 5; ++r) {
      int yy = y + r - 2;
      win[r][4] = (yy >= 0 && yy < HH && xx < WW2)
                    ? base[((size_t)yy * WW2 + xx) * HID_ + c] : 0.f;
    }
    float s = bias;
    #pragma unroll
    for (int r = 0; r < 5; ++r)
      #pragma unroll
      for (int t = 0; t < 5; ++t) s += win[r][t] * wr[r * 5 + t];
    s = gelu_f(s);
    out[((size_t)b * NN + (size_t)y * WW2 + x) * HID_ + c] = s;
    #pragma unroll
    for (int r = 0; r < 5; ++r) {
      win[r][0] = win[r][1]; win[r][1] = win[r][2];
      win[r][2] = win[r][3]; win[r][3] = win[r][4];
    }
  }
}

// ---------------- per-(b,t) stats for mask_soft softmax over n ----------------
__global__ __launch_bounds__(256)
void tdstats_kernel(const float* __restrict__ simT, float* __restrict__ tmax,
                    float* __restrict__ tden) {
  int bt = blockIdx.x;
  int tid = threadIdx.x;
  const float* row = simT + (size_t)bt * NN;
  float m = -3.4e38f;
  for (int i = tid; i < NN; i += 256) m = fmaxf(m, row[i]);
  __shared__ float red[256];
  red[tid] = m;
  __syncthreads();
  for (int s = 128; s > 0; s >>= 1) {
    if (tid < s) red[tid] = fmaxf(red[tid], red[tid + s]);
    __syncthreads();
  }
  float mrow = red[0];
  __syncthreads();
  float ssum = 0.f;
  for (int i = tid; i < NN; i += 256) ssum += __expf(row[i] - mrow);
  red[tid] = ssum;
  __syncthreads();
  for (int s = 128; s > 0; s >>= 1) {
    if (tid < s) red[tid] += red[tid + s];
    __syncthreads();
  }
  if (tid == 0) { tmax[bt] = mrow; tden[bt] = red[0]; }
}

// ---------------- split-K: tdacc += mask_soft @ x ----------------
__global__ __launch_bounds__(192)
void tdgemm_kernel(const float* __restrict__ simT, const float* __restrict__ tmax,
                   const float* __restrict__ tden, const float* __restrict__ xf,
                   float* __restrict__ tdacc) {
  int nch = blockIdx.x, tt4 = blockIdx.y, b = blockIdx.z;
  int t0 = tt4 * 32;
  int n0 = nch * 512;
  __shared__ float wtile[32][64];
  float acc[32] = {};
  int tid = threadIdx.x;
  for (int sub = 0; sub < 8; ++sub) {
    int nb = n0 + sub * 64;
    __syncthreads();
    for (int idx = tid; idx < 2048; idx += 192) {
      int trow = idx >> 6, nn = idx & 63;
      int t = t0 + trow;
      float raw = simT[((size_t)(b * NT_ + t)) * NN + nb + nn];
      wtile[trow][nn] = __expf(raw - tmax[b * NT_ + t]) / tden[b * NT_ + t];
    }
    __syncthreads();
    for (int nn = 0; nn < 64; ++nn) {
      float xv = xf[((size_t)(b * NN + nb + nn)) * DIM_ + tid];
      #pragma unroll
      for (int trow = 0; trow < 32; ++trow) acc[trow] += wtile[trow][nn] * xv;
    }
  }
  #pragma unroll
  for (int trow = 0; trow < 32; ++trow)
    atomicAdd(&tdacc[((size_t)(b * NT_ + t0 + trow)) * DIM_ + tid], acc[trow]);
}

// ---------------- td blend + instance norm ----------------
__global__ __launch_bounds__(64)
void tdfinal_kernel(const float* __restrict__ td, const float* __restrict__ tdacc,
                    const float* __restrict__ sigma, const float* __restrict__ in3w,
                    const float* __restrict__ in3b, float* __restrict__ out) {
  int r = blockIdx.x;          // 0..255
  int lane = threadIdx.x;
  int t = r & (NT_ - 1);
  float sg = sigma[t];
  const float* ta = tdacc + (size_t)r * DIM_;
  const float* tp = td + (size_t)r * DIM_;
  float v0 = sg * tp[lane]       + (1.f - sg) * ta[lane];
  float v1 = sg * tp[lane + 64]  + (1.f - sg) * ta[lane + 64];
  float v2 = sg * tp[lane + 128] + (1.f - sg) * ta[lane + 128];
  float s = v0 + v1 + v2;
  #pragma unroll
  for (int m = 32; m; m >>= 1) s += __shfl_xor(s, m, 64);
  float mu = s * (1.0f / 192.0f);
  float d0 = v0 - mu, d1 = v1 - mu, d2 = v2 - mu;
  float q = d0 * d0 + d1 * d1 + d2 * d2;
  #pragma unroll
  for (int m = 32; m; m >>= 1) q += __shfl_xor(q, m, 64);
  float rs = rsqrtf(q * (1.0f / 192.0f) + 1e-5f);
  float w = in3w[t], bb = in3b[t];
  float* o = out + (size_t)ROWS * DIM_ + (size_t)r * DIM_;
  o[lane]       = d0 * rs * w + bb;
  o[lane + 64]  = d1 * rs * w + bb;
  o[lane + 128] = d2 * rs * w + bb;
}

// ---------------- host launch ----------------
extern "C" void kernel_launch(void* const* d_in, const int* in_sizes, int n_in,
                              void* d_out, int out_size, void* d_ws, size_t ws_size,
                              hipStream_t stream) {
  (void)in_sizes; (void)n_in; (void)out_size; (void)ws_size;
  const float* x          = (const float*)d_in[0];
  const float* td         = (const float*)d_in[1];
  const float* attn_mask  = (const float*)d_in[2];
  const float* wqkv_w     = (const float*)d_in[3];
  const float* wqkv_b     = (const float*)d_in[4];
  const float* rpb_table  = (const float*)d_in[5];
  const float* win_proj_w = (const float*)d_in[6];
  const float* win_proj_b = (const float*)d_in[7];
  const float* wq_w       = (const float*)d_in[8];
  const float* wq_b       = (const float*)d_in[9];
  const float* wk_w       = (const float*)d_in[10];
  const float* wk_b       = (const float*)d_in[11];
  const float* wv_w       = (const float*)d_in[12];
  const float* wv_b       = (const float*)d_in[13];
  const float* atd_scale  = (const float*)d_in[14];
  const float* aca_proj_w = (const float*)d_in[15];
  const float* aca_proj_b = (const float*)d_in[16];
  const float* logit_scale= (const float*)d_in[17];
  const float* fc1_w      = (const float*)d_in[18];
  const float* fc1_b      = (const float*)d_in[19];
  const float* dw_w       = (const float*)d_in[20];
  const float* dw_b       = (const float*)d_in[21];
  const float* fc2_w      = (const float*)d_in[22];
  const float* fc2_b      = (const float*)d_in[23];
  const float* ln1_w      = (const float*)d_in[24];
  const float* ln1_b      = (const float*)d_in[25];
  const float* ln2_w      = (const float*)d_in[26];
  const float* ln2_b      = (const float*)d_in[27];
  const float* in3_w      = (const float*)d_in[28];
  const float* in3_b      = (const float*)d_in[29];
  const float* sigma      = (const float*)d_in[30];
  const int*   rpi        = (const int*)d_in[31];

  float* out = (float*)d_out;

  float* wsf = (float*)d_ws;
  size_t o = 0;
  float* xn    = wsf + o; o += (size_t)ROWS * DIM_;        // 6,291,456
  float* qkv   = wsf + o; o += (size_t)ROWS * 3 * DIM_;    // 18,874,368 (reused as hdn)
  float* obuf  = wsf + o; o += (size_t)ROWS * DIM_;        // 6,291,456
  float* simT  = wsf + o; o += (size_t)NB * NT_ * NN;      // 4,194,304
  float* gridb = wsf + o; o += (size_t)ROWS * HID_;        // 12,582,912
  float* qa    = wsf + o; o += (size_t)ROWS * RD_;         // 655,360
  float* ka    = wsf + o; o += (size_t)NB * NT_ * RD_;     // 5,120
  float* va    = wsf + o; o += (size_t)NB * NT_ * DIM_;    // 49,152
  float* m_i   = wsf + o; o += ROWS;
  float* den_i = wsf + o; o += ROWS;
  float* tmaxb = wsf + o; o += NB * NT_;
  float* tdenb = wsf + o; o += NB * NT_;
  float* tdacc = wsf + o; o += (size_t)NB * NT_ * DIM_;
  int* tk      = (int*)(wsf + o); o += ROWS;
  int* chist   = (int*)(wsf + o); o += NB * 64 * NT_;
  int* coffs   = (int*)(wsf + o); o += NB * 64 * NT_;
  int* sort_row= (int*)(wsf + o); o += ROWS;
  float* hdn = qkv;   // fc1 output reuses the (dead-by-then) qkv region

  // 1. accumulator = shortcut
  hipMemcpyAsync(out, x, (size_t)ROWS * DIM_ * sizeof(float),
                 hipMemcpyDeviceToDevice, stream);
  // 2. xn = LN1(x)
  ln_kernel<<<ROWS / 4, 256, 0, stream>>>(x, ln1_w, ln1_b, xn, ROWS);
  // 3. qkv = xn @ wqkv + b
  gemm64<false, true, false, 0, false><<<dim3(9, ROWS / 64), 256, 0, stream>>>(
      xn, wqkv_w, wqkv_b, qkv, ROWS, 576, 192, 192, nullptr);
  // 4. shifted-window attention
  attn_kernel<true><<<dim3(128, 6), 256, 0, stream>>>(
      qkv, nullptr, rpb_table, rpi, attn_mask, nullptr, obuf);
  // 5. win_proj, scatter-add into accumulator
  gemm64<false, true, false, 1, true><<<dim3(3, ROWS / 64), 256, 0, stream>>>(
      obuf, win_proj_w, win_proj_b, out, ROWS, 192, 192, 192, nullptr);
  // 6. ATD projections
  gemm64<false, true, false, 0, false><<<dim3(1, ROWS / 64), 256, 0, stream>>>(
      xn, wq_w, wq_b, qa, ROWS, 20, 192, 192, nullptr);
  gemm64<false, true, false, 0, false><<<dim3(1, 4), 256, 0, stream>>>(
      td, wk_w, wk_b, ka, NB * NT_, 20, 192, 192, nullptr);
  gemm64<false, true, false, 0, false><<<dim3(3, 4), 256, 0, stream>>>(
      td, wv_w, wv_b, va, NB * NT_, 192, 192, 192, nullptr);
  // 7. L2 normalize qa, ka
  normrows20<<<ROWS / 256, 256, 0, stream>>>(qa, ROWS);
  normrows20<<<1, 256, 0, stream>>>(ka, NB * NT_);
  // 8. sim logits (transposed) + stats + argmax, then probs
  sim1_kernel<<<ROWS / 256, 256, 0, stream>>>(qa, ka, atd_scale, simT, m_i, den_i, tk);
  sim2_kernel<<<(NB * NT_ * NN) / 256, 256, 0, stream>>>(simT, m_i, den_i);
  // 9. x_atd = sim @ va  (A^T gemm, per batch), add into accumulator
  for (int b = 0; b < NB; ++b) {
    gemm64<true, false, false, 0, true><<<dim3(3, NN / 64), 256, 0, stream>>>(
        simT + (size_t)b * NT_ * NN, va + (size_t)b * NT_ * DIM_, nullptr,
        out + (size_t)b * NN * DIM_, NN, 192, 128, NN, nullptr);
  }
  // 10. stable counting sort by tk
  hist_kernel<<<dim3(64, NB), 256, 0, stream>>>(tk, chist);
  offsets_kernel<<<NB, 128, 0, stream>>>(chist, coffs);
  scatter_kernel<<<dim3(64, NB), 256, 0, stream>>>(tk, coffs, sort_row);
  // 11. category attention over sorted groups
  attn_kernel<false><<<dim3(128, 6), 256, 0, stream>>>(
      qkv, sort_row, nullptr, nullptr, nullptr, logit_scale, obuf);
  // 12. aca_proj, scatter-add via sort permutation
  gemm64<false, true, false, 2, true><<<dim3(3, ROWS / 64), 256, 0, stream>>>(
      obuf, aca_proj_w, aca_proj_b, out, ROWS, 192, 192, 192, sort_row);
  // 13. xn2 = LN2(x)
  ln_kernel<<<ROWS / 4, 256, 0, stream>>>(out, ln2_w, ln2_b, xn, ROWS);
  // 14. hdn = gelu(xn2 @ fc1 + b)
  gemm64<false, true, true, 0, false><<<dim3(6, ROWS / 64), 256, 0, stream>>>(
      xn, fc1_w, fc1_b, hdn, ROWS, 384, 192, 192, nullptr);
  // 15. depthwise conv 5x5 + bias + gelu
  dwconv_kernel<<<dim3(8, 128, NB), 384, 0, stream>>>(hdn, dw_w, dw_b, gridb);
  // 16. x += grid @ fc2 + b
  gemm64<false, true, false, 0, true><<<dim3(3, ROWS / 64), 256, 0, stream>>>(
      gridb, fc2_w, fc2_b, out, ROWS, 192, 384, 384, nullptr);
  // 17-18. td refinement: mask_soft = softmax_n(sim^T); tdacc = mask_soft @ x
  tdstats_kernel<<<NB * NT_, 256, 0, stream>>>(simT, tmaxb, tdenb);
  hipMemsetAsync(tdacc, 0, (size_t)NB * NT_ * DIM_ * sizeof(float), stream);
  tdgemm_kernel<<<dim3(32, 4, NB), 192, 0, stream>>>(simT, tmaxb, tdenb, out, tdacc);
  // 19. blend with sigma + instance norm -> out tail
  tdfinal_kernel<<<NB * NT_, 64, 0, stream>>>(td, tdacc, sigma, in3_w, in3_b, out);
}

// Round 3
// 1286.324 us; speedup vs baseline: 1.0147x; 1.0147x over previous
//
#include <hip/hip_runtime.h>
#include <math.h>

// ---------------- constants ----------------
#define NB    2
#define HH    128
#define WW2   128
#define NN    16384            // H*W
#define DIM_  192
#define HEADS_ 6
#define HD_   32
#define NT_   128
#define RD_   20
#define HID_  384
#define ROWS  32768            // B*N
#define HD_SCALE 0.17677669529663687f  // 1/sqrt(32)
#define LOG100   4.6051701859880914f
#define LOGNT    4.852030263919617f    // ln(128)

__device__ __forceinline__ float gelu_f(float v) {
  return 0.5f * v * (1.0f + erff(v * 0.7071067811865475f));
}

// window row (0..32767) -> global token row (b*16384+n), same map for gather & scatter
__device__ __forceinline__ int winmap_row(int r) {
  int b_ = r >> 8;
  int p  = r & 255;
  int b  = b_ >> 6;
  int win = b_ & 63;
  int y = ((win >> 3) << 4) + (p >> 4);
  int x = ((win & 7) << 4) + (p & 15);
  int n = (((y + 8) & 127) << 7) + ((x + 8) & 127);
  return (b << 14) + n;
}

// swin region id along one axis (boundaries at 112 and 120)
__device__ __forceinline__ int rgn(int v) { return (v >= 112 ? 1 : 0) + (v >= 120 ? 1 : 0); }

// ---------------- LayerNorm over 192 (wave per row) ----------------
__global__ __launch_bounds__(256)
void ln_kernel(const float* __restrict__ in, const float* __restrict__ w,
               const float* __restrict__ bv, float* __restrict__ out, int nrows) {
  int wave = threadIdx.x >> 6, lane = threadIdx.x & 63;
  int row = blockIdx.x * 4 + wave;
  if (row >= nrows) return;
  const float* p = in + (size_t)row * DIM_;
  float v0 = p[lane], v1 = p[lane + 64], v2 = p[lane + 128];
  float s = v0 + v1 + v2;
  #pragma unroll
  for (int m = 32; m; m >>= 1) s += __shfl_xor(s, m, 64);
  float mu = s * (1.0f / 192.0f);
  float d0 = v0 - mu, d1 = v1 - mu, d2 = v2 - mu;
  float q = d0 * d0 + d1 * d1 + d2 * d2;
  #pragma unroll
  for (int m = 32; m; m >>= 1) q += __shfl_xor(q, m, 64);
  float rs = rsqrtf(q * (1.0f / 192.0f) + 1e-5f);
  float* o = out + (size_t)row * DIM_;
  o[lane]       = d0 * rs * w[lane]       + bv[lane];
  o[lane + 64]  = d1 * rs * w[lane + 64]  + bv[lane + 64];
  o[lane + 128] = d2 * rs * w[lane + 128] + bv[lane + 128];
}

// ---------------- tiled f32 GEMM: 128x64 tile, 8x4/thread, A staged transposed ----------------
// AT: A stored K-major (A[k*lda+m]); RMODE: 0 none, 1 winmap, 2 rowmap array.
// Requires M % 128 == 0, K % 32 == 0.
template<bool AT, bool BIAS, bool DOGELU, int RMODE, bool ADD>
__global__ __launch_bounds__(256)
void gemm128(const float* __restrict__ A, const float* __restrict__ W,
             const float* __restrict__ bias, float* __restrict__ C,
             int M, int N, int K, int lda, const int* __restrict__ rowmap) {
  __shared__ float As[32][128];   // [k][m]
  __shared__ float Bs[32][64];    // [k][n]
  int tid = threadIdx.x;
  int tx = tid & 15, ty = tid >> 4;        // tx: n/4, ty: m/8
  int m0 = blockIdx.y * 128, n0 = blockIdx.x * 64;
  float acc[8][4] = {};
  for (int k0 = 0; k0 < K; k0 += 32) {
    if (!AT) {
      // load A[m][k] rows, write transposed As[k][m]
      #pragma unroll
      for (int q = 0; q < 4; ++q) {
        int i = tid * 4 + q;               // 0..1023
        int r = i >> 3, c4 = (i & 7) << 2; // r: row 0..127, c4: k-offset 0,4,..,28
        float4 v = *(const float4*)(A + (size_t)(m0 + r) * lda + k0 + c4);
        As[c4 + 0][r] = v.x; As[c4 + 1][r] = v.y; As[c4 + 2][r] = v.z; As[c4 + 3][r] = v.w;
      }
    } else {
      // A already K-major: straight b128 copy
      #pragma unroll
      for (int q = 0; q < 4; ++q) {
        int i = q * 256 + tid;             // 0..1023
        int kc = i >> 5, mr4 = (i & 31) << 2;
        float4 v = *(const float4*)(A + (size_t)(k0 + kc) * lda + m0 + mr4);
        *(float4*)&As[kc][mr4] = v;
      }
    }
    #pragma unroll
    for (int q = 0; q < 2; ++q) {
      int i = tid * 2 + q;
      int kc = i >> 4, nc = (i & 15) << 2;
      int col = n0 + nc;
      float4 v = make_float4(0.f, 0.f, 0.f, 0.f);
      if (col + 3 < N) {
        v = *(const float4*)(W + (size_t)(k0 + kc) * N + col);
      } else {
        float t[4] = {0.f, 0.f, 0.f, 0.f};
        #pragma unroll
        for (int e = 0; e < 4; ++e) if (col + e < N) t[e] = W[(size_t)(k0 + kc) * N + col + e];
        v = make_float4(t[0], t[1], t[2], t[3]);
      }
      *(float4*)&Bs[kc][nc] = v;
    }
    __syncthreads();
    #pragma unroll
    for (int kk = 0; kk < 32; ++kk) {
      float4 a0 = *(const float4*)&As[kk][ty * 8];
      float4 a1 = *(const float4*)&As[kk][ty * 8 + 4];
      float4 b  = *(const float4*)&Bs[kk][tx * 4];
      float av[8] = {a0.x, a0.y, a0.z, a0.w, a1.x, a1.y, a1.z, a1.w};
      #pragma unroll
      for (int ii = 0; ii < 8; ++ii) {
        acc[ii][0] += av[ii] * b.x; acc[ii][1] += av[ii] * b.y;
        acc[ii][2] += av[ii] * b.z; acc[ii][3] += av[ii] * b.w;
      }
    }
    __syncthreads();
  }
  #pragma unroll
  for (int ii = 0; ii < 8; ++ii) {
    int row = m0 + ty * 8 + ii;
    int drow;
    if (RMODE == 1) drow = winmap_row(row);
    else if (RMODE == 2) drow = rowmap[row];
    else drow = row;
    float* crow = C + (size_t)drow * N;
    #pragma unroll
    for (int j = 0; j < 4; ++j) {
      int col = n0 + tx * 4 + j;
      if (col < N) {
        float v = acc[ii][j];
        if (BIAS) v += bias[col];
        if (DOGELU) v = gelu_f(v);
        if (ADD) crow[col] += v; else crow[col] = v;
      }
    }
  }
}

// ---------------- merged flash attention (win + cat), 256 queries/block, K/V in 2x128 chunks ----
// blockIdx.z == 0: shifted-window MSA (computed rpi/mask, rpb staged in LDS)
// blockIdx.z == 1: category MSA (rows via sort_row, scale=exp(min(ls,ln100)))
__global__ __launch_bounds__(256)
void attn2_kernel(const float* __restrict__ qkv, const int* __restrict__ sort_row,
                  const float* __restrict__ rpb_table, const float* __restrict__ ls_ptr,
                  float* __restrict__ obufW, float* __restrict__ obufC) {
  __shared__ float Ks[128][32];
  __shared__ float Vs[128][32];
  __shared__ float rpb_s[964];
  int b_ = blockIdx.x, head = blockIdx.y;
  bool IS_WIN = (blockIdx.z == 0);
  int tid = threadIdx.x;

  if (IS_WIN) {
    for (int idx = tid; idx < 961; idx += 256) rpb_s[idx] = rpb_table[idx * HEADS_ + head];
  }

  // query
  int gq = b_ * 256 + tid;
  int srcq = IS_WIN ? winmap_row(gq) : sort_row[gq];
  float qr[32];
  {
    const float4* rowp = (const float4*)(qkv + (size_t)srcq * 576);
    #pragma unroll
    for (int q4 = 0; q4 < 8; ++q4) {
      float4 v = rowp[head * 8 + q4];
      qr[q4 * 4] = v.x; qr[q4 * 4 + 1] = v.y; qr[q4 * 4 + 2] = v.z; qr[q4 * 4 + 3] = v.w;
    }
  }
  float scale = IS_WIN ? HD_SCALE : __expf(fminf(ls_ptr[0], LOG100));

  // query-side window geometry (win blocks only)
  int win = b_ & 63;
  int wy = (win >> 3) << 4, wx = (win & 7) << 4;
  int py = tid >> 4, px = tid & 15;
  int ri = rgn(wy + py) * 3 + rgn(wx + px);

  float m = -3.4e38f, l = 0.f, acc[32];
  #pragma unroll
  for (int d = 0; d < 32; ++d) acc[d] = 0.f;

  for (int c0 = 0; c0 < 256; c0 += 128) {
    __syncthreads();
    // stage 128 keys+values
    #pragma unroll
    for (int it = 0; it < 4; ++it) {
      int j = it * 32 + (tid >> 3);
      int q4 = tid & 7;
      int src = IS_WIN ? winmap_row(b_ * 256 + c0 + j) : sort_row[b_ * 256 + c0 + j];
      const float4* rowp = (const float4*)(qkv + (size_t)src * 576);
      *(float4*)&Ks[j][q4 << 2] = rowp[48 + head * 8 + q4];
      *(float4*)&Vs[j][q4 << 2] = rowp[96 + head * 8 + q4];
    }
    __syncthreads();

    for (int j0 = 0; j0 < 128; j0 += 16) {
      float s[16];
      #pragma unroll
      for (int jj = 0; jj < 16; ++jj) {
        const float* kp = Ks[j0 + jj];
        float4 k0v = *(const float4*)(kp + 0),  k1v = *(const float4*)(kp + 4);
        float4 k2v = *(const float4*)(kp + 8),  k3v = *(const float4*)(kp + 12);
        float4 k4v = *(const float4*)(kp + 16), k5v = *(const float4*)(kp + 20);
        float4 k6v = *(const float4*)(kp + 24), k7v = *(const float4*)(kp + 28);
        float a = qr[0]*k0v.x + qr[1]*k0v.y + qr[2]*k0v.z + qr[3]*k0v.w
                + qr[4]*k1v.x + qr[5]*k1v.y + qr[6]*k1v.z + qr[7]*k1v.w
                + qr[8]*k2v.x + qr[9]*k2v.y + qr[10]*k2v.z + qr[11]*k2v.w
                + qr[12]*k3v.x + qr[13]*k3v.y + qr[14]*k3v.z + qr[15]*k3v.w
                + qr[16]*k4v.x + qr[17]*k4v.y + qr[18]*k4v.z + qr[19]*k4v.w
                + qr[20]*k5v.x + qr[21]*k5v.y + qr[22]*k5v.z + qr[23]*k5v.w
                + qr[24]*k6v.x + qr[25]*k6v.y + qr[26]*k6v.z + qr[27]*k6v.w
                + qr[28]*k7v.x + qr[29]*k7v.y + qr[30]*k7v.z + qr[31]*k7v.w;
        a *= scale;
        if (IS_WIN) {
          int jab = c0 + j0 + jj;
          int jy = jab >> 4, jx = jab & 15;
          int idx = (py - jy + 15) * 31 + (px - jx + 15);
          int rj = rgn(wy + jy) * 3 + rgn(wx + jx);
          a += rpb_s[idx] + (ri != rj ? -100.0f : 0.0f);
        }
        s[jj] = a;
      }
      float cm = s[0];
      #pragma unroll
      for (int jj = 1; jj < 16; ++jj) cm = fmaxf(cm, s[jj]);
      float mn = fmaxf(m, cm);
      float corr = __expf(m - mn);
      l *= corr;
      #pragma unroll
      for (int d = 0; d < 32; ++d) acc[d] *= corr;
      #pragma unroll
      for (int jj = 0; jj < 16; ++jj) {
        float p = __expf(s[jj] - mn);
        l += p;
        const float* vp = Vs[j0 + jj];
        #pragma unroll
        for (int d = 0; d < 32; ++d) acc[d] += p * vp[d];
      }
      m = mn;
    }
  }
  float inv = 1.0f / l;
  float* obuf = IS_WIN ? obufW : obufC;
  float* op = obuf + ((size_t)(b_ * 256 + tid)) * DIM_ + head * HD_;
  #pragma unroll
  for (int d4 = 0; d4 < 8; ++d4) {
    float4 v = make_float4(acc[d4 * 4] * inv, acc[d4 * 4 + 1] * inv,
                           acc[d4 * 4 + 2] * inv, acc[d4 * 4 + 3] * inv);
    *(float4*)(op + d4 * 4) = v;
  }
}

// ---------------- row L2-normalize, width 20 ----------------
__global__ __launch_bounds__(256)
void normrows20(float* __restrict__ p, int rows) {
  int r = blockIdx.x * 256 + threadIdx.x;
  if (r >= rows) return;
  float4* rp = (float4*)(p + (size_t)r * RD_);
  float4 v[5];
  float s = 0.f;
  #pragma unroll
  for (int e = 0; e < 5; ++e) {
    v[e] = rp[e];
    s += v[e].x * v[e].x + v[e].y * v[e].y + v[e].z * v[e].z + v[e].w * v[e].w;
  }
  float inv = 1.0f / fmaxf(sqrtf(s), 1e-12f);
  #pragma unroll
  for (int e = 0; e < 5; ++e) {
    v[e].x *= inv; v[e].y *= inv; v[e].z *= inv; v[e].w *= inv;
    rp[e] = v[e];
  }
}

// ---------------- sim logits (stored transposed) + row stats + argmax ----------------
__global__ __launch_bounds__(256)
void sim1_kernel(const float* __restrict__ qa, const float* __restrict__ ka,
                 const float* __restrict__ atd_scale, float* __restrict__ simT,
                 float* __restrict__ m_out, float* __restrict__ den_out, int* __restrict__ tk) {
  __shared__ float kas[NT_ * RD_];
  __shared__ float scl[NT_];
  int tid = threadIdx.x;
  int gi = blockIdx.x * 256 + tid;         // 0..32767
  int b = blockIdx.x >> 6;
  for (int idx = tid; idx < NT_ * RD_; idx += 256) kas[idx] = ka[b * NT_ * RD_ + idx];
  for (int t = tid; t < NT_; t += 256)
    scl[t] = 1.0f + fminf(fmaxf(atd_scale[t], 0.f), 1.f) * LOGNT;
  __syncthreads();
  float q[20];
  const float4* qp = (const float4*)(qa + (size_t)gi * RD_);
  #pragma unroll
  for (int e = 0; e < 5; ++e) {
    float4 v = qp[e];
    q[e * 4] = v.x; q[e * 4 + 1] = v.y; q[e * 4 + 2] = v.z; q[e * 4 + 3] = v.w;
  }
  int n = gi & (NN - 1);
  float m = -3.4e38f, l = 0.f;
  int am = 0;
  float* srow = simT + (size_t)b * NT_ * NN + n;
  for (int t = 0; t < NT_; ++t) {
    const float* kp = &kas[t * RD_];
    float d = 0.f;
    #pragma unroll
    for (int e = 0; e < 20; ++e) d += q[e] * kp[e];
    d *= scl[t];
    srow[(size_t)t * NN] = d;
    if (d > m) { l = l * __expf(m - d) + 1.0f; m = d; am = t; }
    else       { l += __expf(d - m); }
  }
  m_out[gi] = m; den_out[gi] = l; tk[gi] = am;
}

// ---------------- normalize logits -> probs (in place on simT) ----------------
__global__ __launch_bounds__(256)
void sim2_kernel(float* __restrict__ simT, const float* __restrict__ m_i,
                 const float* __restrict__ den_i) {
  size_t idx = (size_t)blockIdx.x * 256 + threadIdx.x;   // 4,194,304 total
  int b = (int)(idx >> 21);
  int n = (int)(idx & (NN - 1));
  int gi = (b << 14) + n;
  float r = simT[idx];
  simT[idx] = __expf(r - m_i[gi]) / den_i[gi];
}

// ---------------- counting sort (stable) ----------------
__global__ __launch_bounds__(256)
void hist_kernel(const int* __restrict__ tk, int* __restrict__ chist) {
  __shared__ int h[NT_];
  int tid = threadIdx.x, ch = blockIdx.x, b = blockIdx.y;
  if (tid < NT_) h[tid] = 0;
  __syncthreads();
  int bin = tk[b * NN + ch * 256 + tid];
  atomicAdd(&h[bin], 1);
  __syncthreads();
  if (tid < NT_) chist[(b * 64 + ch) * NT_ + tid] = h[tid];
}

__global__ __launch_bounds__(128)
void offsets_kernel(const int* __restrict__ chist, int* __restrict__ offs) {
  int b = blockIdx.x, bin = threadIdx.x;
  int total = 0;
  for (int ch = 0; ch < 64; ++ch) total += chist[(b * 64 + ch) * NT_ + bin];
  __shared__ int sc[NT_];
  sc[bin] = total;
  __syncthreads();
  int base = 0;
  for (int i = 0; i < bin; ++i) base += sc[i];
  int run = base;
  for (int ch = 0; ch < 64; ++ch) {
    offs[(b * 64 + ch) * NT_ + bin] = run;
    run += chist[(b * 64 + ch) * NT_ + bin];
  }
}

__global__ __launch_bounds__(256)
void scatter_kernel(const int* __restrict__ tk, const int* __restrict__ offs,
                    int* __restrict__ sort_row) {
  __shared__ int bins[256];
  int tid = threadIdx.x, ch = blockIdx.x, b = blockIdx.y;
  int i = ch * 256 + tid;
  int bin = tk[b * NN + i];
  bins[tid] = bin;
  __syncthreads();
  int rank = 0;
  for (int j = 0; j < tid; ++j) rank += (bins[j] == bin) ? 1 : 0;
  int pos = offs[(b * 64 + ch) * NT_ + bin] + rank;
  sort_row[b * NN + pos] = b * NN + i;
}

// ---------------- depthwise 5x5 conv + bias + gelu ----------------
__global__ __launch_bounds__(384)
void dwconv_kernel(const float* __restrict__ hdn, const float* __restrict__ wgt,
                   const float* __restrict__ bv, float* __restrict__ out) {
  int c = threadIdx.x;
  int xt = blockIdx.x, y = blockIdx.y, b = blockIdx.z;
  float wr[25];
  #pragma unroll
  for (int t = 0; t < 25; ++t) wr[t] = wgt[c * 25 + t];
  float bias = bv[c];
  int x0 = xt * 16;
  const float* base = hdn + (size_t)b * NN * HID_;
  float win[5][5];
  #pragma unroll
  for (int r = 0; r < 5; ++r) {
    int yy = y + r - 2;
    #pragma unroll
    for (int t = 0; t < 4; ++t) {
      int xx = x0 - 2 + t;
      win[r][t] = (yy >= 0 && yy < HH && xx >= 0 && xx < WW2)
                    ? base[((size_t)yy * WW2 + xx) * HID_ + c] : 0.f;
    }
  }
  for (int x = x0; x < x0 + 16; ++x) {
    int xx = x + 2;
    #pragma unroll
    for (int r = 0; r < 5; ++r) {
      int yy = y + r - 2;
      win[r][4] = (yy >= 0 && yy < HH && xx < WW2)
                    ? base[((size_t)yy * WW2 + xx) * HID_ + c] : 0.f;
    }
    float s = bias;
    #pragma unroll
    for (int r = 0; r < 5; ++r)
      #pragma unroll
      for (int t = 0; t < 5; ++t) s += win[r][t] * wr[r * 5 + t];
    s = gelu_f(s);
    out[((size_t)b * NN + (size_t)y * WW2 + x) * HID_ + c] = s;
    #pragma unroll
    for (int r = 0; r < 5; ++r) {
      win[r][0] = win[r][1]; win[r][1] = win[r][2];
      win[r][2] = win[r][3]; win[r][3] = win[r][4];
    }
  }
}

// ---------------- per-(b,t) stats for mask_soft softmax over n ----------------
__global__ __launch_bounds__(256)
void tdstats_kernel(const float* __restrict__ simT, float* __restrict__ tmax,
                    float* __restrict__ tden) {
  int bt = blockIdx.x;
  int tid = threadIdx.x;
  const float* row = simT + (size_t)bt * NN;
  float m = -3.4e38f;
  for (int i = tid; i < NN; i += 256) m = fmaxf(m, row[i]);
  __shared__ float red[256];
  red[tid] = m;
  __syncthreads();
  for (int s = 128; s > 0; s >>= 1) {
    if (tid < s) red[tid] = fmaxf(red[tid], red[tid + s]);
    __syncthreads();
  }
  float mrow = red[0];
  __syncthreads();
  float ssum = 0.f;
  for (int i = tid; i < NN; i += 256) ssum += __expf(row[i] - mrow);
  red[tid] = ssum;
  __syncthreads();
  for (int s = 128; s > 0; s >>= 1) {
    if (tid < s) red[tid] += red[tid + s];
    __syncthreads();
  }
  if (tid == 0) { tmax[bt] = mrow; tden[bt] = red[0]; }
}

// ---------------- split-K: tdacc += mask_soft @ x ----------------
__global__ __launch_bounds__(192)
void tdgemm_kernel(const float* __restrict__ simT, const float* __restrict__ tmax,
                   const float* __restrict__ tden, const float* __restrict__ xf,
                   float* __restrict__ tdacc) {
  int nch = blockIdx.x, tt4 = blockIdx.y, b = blockIdx.z;
  int t0 = tt4 * 32;
  int n0 = nch * 512;
  __shared__ float wtile[32][64];
  float acc[32] = {};
  int tid = threadIdx.x;
  for (int sub = 0; sub < 8; ++sub) {
    int nb = n0 + sub * 64;
    __syncthreads();
    for (int idx = tid; idx < 2048; idx += 192) {
      int trow = idx >> 6, nn = idx & 63;
      int t = t0 + trow;
      float raw = simT[((size_t)(b * NT_ + t)) * NN + nb + nn];
      wtile[trow][nn] = __expf(raw - tmax[b * NT_ + t]) / tden[b * NT_ + t];
    }
    __syncthreads();
    for (int nn = 0; nn < 64; ++nn) {
      float xv = xf[((size_t)(b * NN + nb + nn)) * DIM_ + tid];
      #pragma unroll
      for (int trow = 0; trow < 32; ++trow) acc[trow] += wtile[trow][nn] * xv;
    }
  }
  #pragma unroll
  for (int trow = 0; trow < 32; ++trow)
    atomicAdd(&tdacc[((size_t)(b * NT_ + t0 + trow)) * DIM_ + tid], acc[trow]);
}

// ---------------- td blend + instance norm ----------------
__global__ __launch_bounds__(64)
void tdfinal_kernel(const float* __restrict__ td, const float* __restrict__ tdacc,
                    const float* __restrict__ sigma, const float* __restrict__ in3w,
                    const float* __restrict__ in3b, float* __restrict__ out) {
  int r = blockIdx.x;          // 0..255
  int lane = threadIdx.x;
  int t = r & (NT_ - 1);
  float sg = sigma[t];
  const float* ta = tdacc + (size_t)r * DIM_;
  const float* tp = td + (size_t)r * DIM_;
  float v0 = sg * tp[lane]       + (1.f - sg) * ta[lane];
  float v1 = sg * tp[lane + 64]  + (1.f - sg) * ta[lane + 64];
  float v2 = sg * tp[lane + 128] + (1.f - sg) * ta[lane + 128];
  float s = v0 + v1 + v2;
  #pragma unroll
  for (int m = 32; m; m >>= 1) s += __shfl_xor(s, m, 64);
  float mu = s * (1.0f / 192.0f);
  float d0 = v0 - mu, d1 = v1 - mu, d2 = v2 - mu;
  float q = d0 * d0 + d1 * d1 + d2 * d2;
  #pragma unroll
  for (int m = 32; m; m >>= 1) q += __shfl_xor(q, m, 64);
  float rs = rsqrtf(q * (1.0f / 192.0f) + 1e-5f);
  float w = in3w[t], bb = in3b[t];
  float* o = out + (size_t)ROWS * DIM_ + (size_t)r * DIM_;
  o[lane]       = d0 * rs * w + bb;
  o[lane + 64]  = d1 * rs * w + bb;
  o[lane + 128] = d2 * rs * w + bb;
}

// ---------------- host launch ----------------
extern "C" void kernel_launch(void* const* d_in, const int* in_sizes, int n_in,
                              void* d_out, int out_size, void* d_ws, size_t ws_size,
                              hipStream_t stream) {
  (void)in_sizes; (void)n_in; (void)out_size; (void)ws_size;
  const float* x          = (const float*)d_in[0];
  const float* td         = (const float*)d_in[1];
  const float* wqkv_w     = (const float*)d_in[3];
  const float* wqkv_b     = (const float*)d_in[4];
  const float* rpb_table  = (const float*)d_in[5];
  const float* win_proj_w = (const float*)d_in[6];
  const float* win_proj_b = (const float*)d_in[7];
  const float* wq_w       = (const float*)d_in[8];
  const float* wq_b       = (const float*)d_in[9];
  const float* wk_w       = (const float*)d_in[10];
  const float* wk_b       = (const float*)d_in[11];
  const float* wv_w       = (const float*)d_in[12];
  const float* wv_b       = (const float*)d_in[13];
  const float* atd_scale  = (const float*)d_in[14];
  const float* aca_proj_w = (const float*)d_in[15];
  const float* aca_proj_b = (const float*)d_in[16];
  const float* logit_scale= (const float*)d_in[17];
  const float* fc1_w      = (const float*)d_in[18];
  const float* fc1_b      = (const float*)d_in[19];
  const float* dw_w       = (const float*)d_in[20];
  const float* dw_b       = (const float*)d_in[21];
  const float* fc2_w      = (const float*)d_in[22];
  const float* fc2_b      = (const float*)d_in[23];
  const float* ln1_w      = (const float*)d_in[24];
  const float* ln1_b      = (const float*)d_in[25];
  const float* ln2_w      = (const float*)d_in[26];
  const float* ln2_b      = (const float*)d_in[27];
  const float* in3_w      = (const float*)d_in[28];
  const float* in3_b      = (const float*)d_in[29];
  const float* sigma      = (const float*)d_in[30];

  float* out = (float*)d_out;

  float* wsf = (float*)d_ws;
  size_t o = 0;
  float* xn    = wsf + o; o += (size_t)ROWS * DIM_;
  float* qkv   = wsf + o; o += (size_t)ROWS * 3 * DIM_;    // reused as hdn
  float* obufW = wsf + o; o += (size_t)ROWS * DIM_;
  float* simT  = wsf + o; o += (size_t)NB * NT_ * NN;
  float* gridb = wsf + o; o += (size_t)ROWS * HID_;        // aliased as obufC early
  float* qa    = wsf + o; o += (size_t)ROWS * RD_;
  float* ka    = wsf + o; o += (size_t)NB * NT_ * RD_;
  float* va    = wsf + o; o += (size_t)NB * NT_ * DIM_;
  float* m_i   = wsf + o; o += ROWS;
  float* den_i = wsf + o; o += ROWS;
  float* tmaxb = wsf + o; o += NB * NT_;
  float* tdenb = wsf + o; o += NB * NT_;
  float* tdacc = wsf + o; o += (size_t)NB * NT_ * DIM_;
  int* tk      = (int*)(wsf + o); o += ROWS;
  int* chist   = (int*)(wsf + o); o += NB * 64 * NT_;
  int* coffs   = (int*)(wsf + o); o += NB * 64 * NT_;
  int* sort_row= (int*)(wsf + o); o += ROWS;
  float* hdn   = qkv;     // fc1 output reuses dead qkv region
  float* obufC = gridb;   // cat-attn output reuses gridb (dead until dwconv)

  // 1. accumulator = shortcut
  hipMemcpyAsync(out, x, (size_t)ROWS * DIM_ * sizeof(float),
                 hipMemcpyDeviceToDevice, stream);
  // 2. xn = LN1(x)
  ln_kernel<<<ROWS / 4, 256, 0, stream>>>(x, ln1_w, ln1_b, xn, ROWS);
  // 3. qkv = xn @ wqkv + b
  gemm128<false, true, false, 0, false><<<dim3(9, ROWS / 128), 256, 0, stream>>>(
      xn, wqkv_w, wqkv_b, qkv, ROWS, 576, 192, 192, nullptr);
  // 4. ATD projections
  gemm128<false, true, false, 0, false><<<dim3(1, ROWS / 128), 256, 0, stream>>>(
      xn, wq_w, wq_b, qa, ROWS, 20, 192, 192, nullptr);
  gemm128<false, true, false, 0, false><<<dim3(1, 2), 256, 0, stream>>>(
      td, wk_w, wk_b, ka, NB * NT_, 20, 192, 192, nullptr);
  gemm128<false, true, false, 0, false><<<dim3(3, 2), 256, 0, stream>>>(
      td, wv_w, wv_b, va, NB * NT_, 192, 192, 192, nullptr);
  // 5. L2 normalize qa, ka
  normrows20<<<ROWS / 256, 256, 0, stream>>>(qa, ROWS);
  normrows20<<<1, 256, 0, stream>>>(ka, NB * NT_);
  // 6. sim logits (transposed) + stats + argmax, then probs
  sim1_kernel<<<ROWS / 256, 256, 0, stream>>>(qa, ka, atd_scale, simT, m_i, den_i, tk);
  sim2_kernel<<<(NB * NT_ * NN) / 256, 256, 0, stream>>>(simT, m_i, den_i);
  // 7. stable counting sort by tk
  hist_kernel<<<dim3(64, NB), 256, 0, stream>>>(tk, chist);
  offsets_kernel<<<NB, 128, 0, stream>>>(chist, coffs);
  scatter_kernel<<<dim3(64, NB), 256, 0, stream>>>(tk, coffs, sort_row);
  // 8. merged attention: z=0 window -> obufW, z=1 category -> obufC
  attn2_kernel<<<dim3(128, 6, 2), 256, 0, stream>>>(
      qkv, sort_row, rpb_table, logit_scale, obufW, obufC);
  // 9. projections / x_atd, all scatter-add into accumulator
  gemm128<false, true, false, 1, true><<<dim3(3, ROWS / 128), 256, 0, stream>>>(
      obufW, win_proj_w, win_proj_b, out, ROWS, 192, 192, 192, nullptr);
  gemm128<false, true, false, 2, true><<<dim3(3, ROWS / 128), 256, 0, stream>>>(
      obufC, aca_proj_w, aca_proj_b, out, ROWS, 192, 192, 192, sort_row);
  for (int b = 0; b < NB; ++b) {
    gemm128<true, false, false, 0, true><<<dim3(3, NN / 128), 256, 0, stream>>>(
        simT + (size_t)b * NT_ * NN, va + (size_t)b * NT_ * DIM_, nullptr,
        out + (size_t)b * NN * DIM_, NN, 192, 128, NN, nullptr);
  }
  // 10. xn2 = LN2(x)
  ln_kernel<<<ROWS / 4, 256, 0, stream>>>(out, ln2_w, ln2_b, xn, ROWS);
  // 11. hdn = gelu(xn2 @ fc1 + b)
  gemm128<false, true, true, 0, false><<<dim3(6, ROWS / 128), 256, 0, stream>>>(
      xn, fc1_w, fc1_b, hdn, ROWS, 384, 192, 192, nullptr);
  // 12. depthwise conv 5x5 + bias + gelu
  dwconv_kernel<<<dim3(8, 128, NB), 384, 0, stream>>>(hdn, dw_w, dw_b, gridb);
  // 13. x += grid @ fc2 + b
  gemm128<false, true, false, 0, true><<<dim3(3, ROWS / 128), 256, 0, stream>>>(
      gridb, fc2_w, fc2_b, out, ROWS, 192, 384, 384, nullptr);
  // 14-15. td refinement
  tdstats_kernel<<<NB * NT_, 256, 0, stream>>>(simT, tmaxb, tdenb);
  hipMemsetAsync(tdacc, 0, (size_t)NB * NT_ * DIM_ * sizeof(float), stream);
  tdgemm_kernel<<<dim3(32, 4, NB), 192, 0, stream>>>(simT, tmaxb, tdenb, out, tdacc);
  // 16. blend with sigma + instance norm -> out tail
  tdfinal_kernel<<<NB * NT_, 64, 0, stream>>>(td, tdacc, sigma, in3_w, in3_b, out);
}

// Round 9
// 1037.314 us; speedup vs baseline: 1.2583x; 1.2401x over previous
//
#include <hip/hip_runtime.h>
#include <math.h>

// ---------------- constants ----------------
#define NB    2
#define HH    128
#define WW2   128
#define NN    16384            // H*W
#define DIM_  192
#define HEADS_ 6
#define HD_   32
#define NT_   128
#define RD_   20
#define HID_  384
#define ROWS  32768            // B*N
#define HD_SCALE 0.17677669529663687f  // 1/sqrt(32)
#define LOG100   4.6051701859880914f
#define LOGNT    4.852030263919617f    // ln(128)

typedef __attribute__((ext_vector_type(8))) short s16x8;   // 8 bf16 (guide-verified MFMA frag)
typedef __attribute__((ext_vector_type(4))) float f32x4;

// bf16 (stored as short) <-> f32, RNE
__device__ __forceinline__ float b2f(short h) {
  unsigned u = ((unsigned)(unsigned short)h) << 16;
  return __builtin_bit_cast(float, u);
}
__device__ __forceinline__ short f2b(float f) {
  unsigned u = __builtin_bit_cast(unsigned, f);
  u += 0x7fffu + ((u >> 16) & 1u);
  return (short)(u >> 16);
}

__device__ __forceinline__ float gelu_f(float v) {
  return 0.5f * v * (1.0f + erff(v * 0.7071067811865475f));
}

// window row (0..32767) -> global token row; same map for gather & scatter
__device__ __forceinline__ int winmap_row(int r) {
  int b_ = r >> 8;
  int p  = r & 255;
  int b  = b_ >> 6;
  int win = b_ & 63;
  int y = ((win >> 3) << 4) + (p >> 4);
  int x = ((win & 7) << 4) + (p & 15);
  int n = (((y + 8) & 127) << 7) + ((x + 8) & 127);
  return (b << 14) + n;
}

// swin region id along one axis (boundaries at 112 and 120)
__device__ __forceinline__ int rgn(int v) { return (v >= 112 ? 1 : 0) + (v >= 120 ? 1 : 0); }

// ---------------- LayerNorm over 192, writes f32 + bf16 ----------------
__global__ __launch_bounds__(256)
void ln_kernel(const float* __restrict__ in, const float* __restrict__ w,
               const float* __restrict__ bv, float* __restrict__ out,
               short* __restrict__ outh, int nrows) {
  int wave = threadIdx.x >> 6, lane = threadIdx.x & 63;
  int row = blockIdx.x * 4 + wave;
  if (row >= nrows) return;
  const float* p = in + (size_t)row * DIM_;
  float v0 = p[lane], v1 = p[lane + 64], v2 = p[lane + 128];
  float s = v0 + v1 + v2;
  #pragma unroll
  for (int m = 32; m; m >>= 1) s += __shfl_xor(s, m, 64);
  float mu = s * (1.0f / 192.0f);
  float d0 = v0 - mu, d1 = v1 - mu, d2 = v2 - mu;
  float q = d0 * d0 + d1 * d1 + d2 * d2;
  #pragma unroll
  for (int m = 32; m; m >>= 1) q += __shfl_xor(q, m, 64);
  float rs = rsqrtf(q * (1.0f / 192.0f) + 1e-5f);
  float r0 = d0 * rs * w[lane]       + bv[lane];
  float r1 = d1 * rs * w[lane + 64]  + bv[lane + 64];
  float r2 = d2 * rs * w[lane + 128] + bv[lane + 128];
  float* o = out + (size_t)row * DIM_;
  o[lane] = r0; o[lane + 64] = r1; o[lane + 128] = r2;
  short* oh = outh + (size_t)row * DIM_;
  oh[lane] = f2b(r0); oh[lane + 64] = f2b(r1); oh[lane + 128] = f2b(r2);
}

// ---------------- transpose + cast: W[K][N] f32 -> Wt[N][K] bf16 ----------------
__global__ __launch_bounds__(256)
void transcast(const float* __restrict__ W, short* __restrict__ Wt, int K, int N) {
  __shared__ float tile[32][33];
  int bx = blockIdx.x * 32, by = blockIdx.y * 32;   // bx: n, by: k
  int tx = threadIdx.x & 31, ty = threadIdx.x >> 5; // 32 x 8
  #pragma unroll
  for (int j = 0; j < 32; j += 8)
    tile[ty + j][tx] = W[(size_t)(by + ty + j) * N + bx + tx];
  __syncthreads();
  #pragma unroll
  for (int j = 0; j < 32; j += 8)
    Wt[(size_t)(bx + ty + j) * K + by + tx] = f2b(tile[tx][ty + j]);
}

// ---------------- bf16 MFMA GEMM: C = act(Ah @ Wt^T + bias) ----------------
// Ah: [M][K] bf16 row-major, Wt: [N][K] bf16 row-major (pre-transposed weight).
// BM=128, BN=64, BK=32; 4 waves in 2x2; wave tile 64x32 (4x2 frags of 16x16x32).
// RMODE: 0 none, 1 winmap, 2 rowmap.  OUTMODE: 0 f32 store, 1 f32 add, 2 bf16 store.
template<int KSTEPS, bool BIAS, bool DOGELU, int RMODE, int OUTMODE>
__global__ __launch_bounds__(256)
void gemm_mfma(const short* __restrict__ Ah, const short* __restrict__ Wt,
               const float* __restrict__ bias, float* __restrict__ C,
               short* __restrict__ Ch, int N, const int* __restrict__ rowmap) {
  constexpr int K = KSTEPS * 32;
  __shared__ short Asm[128][40];
  __shared__ short Bsm[64][40];
  int tid = threadIdx.x;
  int m0 = blockIdx.y * 128, n0 = blockIdx.x * 64;
  int w = tid >> 6, lane = tid & 63;
  int wm = w >> 1, wn = w & 1;
  int g = lane >> 4, r16 = lane & 15;
  f32x4 acc[4][2] = {};
  int srow = tid >> 1, shalf = tid & 1;
  const short* aptr = Ah + (size_t)(m0 + srow) * K + shalf * 16;
  const short* bptr = Wt + (size_t)(n0 + (srow & 63)) * K + shalf * 16; // deref only tid<128
  for (int ks = 0; ks < KSTEPS; ++ks) {
    s16x8 a0 = *(const s16x8*)(aptr);
    s16x8 a1 = *(const s16x8*)(aptr + 8);
    aptr += 32;
    *(s16x8*)&Asm[srow][shalf * 16]     = a0;
    *(s16x8*)&Asm[srow][shalf * 16 + 8] = a1;
    if (tid < 128) {
      s16x8 b0 = *(const s16x8*)(bptr);
      s16x8 b1 = *(const s16x8*)(bptr + 8);
      *(s16x8*)&Bsm[srow][shalf * 16]     = b0;
      *(s16x8*)&Bsm[srow][shalf * 16 + 8] = b1;
    }
    bptr += 32;
    __syncthreads();
    s16x8 af[4], bfr[2];
    #pragma unroll
    for (int mi = 0; mi < 4; ++mi)
      af[mi] = *(const s16x8*)&Asm[wm * 64 + mi * 16 + r16][g * 8];
    #pragma unroll
    for (int ni = 0; ni < 2; ++ni)
      bfr[ni] = *(const s16x8*)&Bsm[wn * 32 + ni * 16 + r16][g * 8];
    #pragma unroll
    for (int mi = 0; mi < 4; ++mi)
      #pragma unroll
      for (int ni = 0; ni < 2; ++ni)
        acc[mi][ni] = __builtin_amdgcn_mfma_f32_16x16x32_bf16(af[mi], bfr[ni], acc[mi][ni], 0, 0, 0);
    __syncthreads();
  }
  #pragma unroll
  for (int mi = 0; mi < 4; ++mi) {
    #pragma unroll
    for (int i = 0; i < 4; ++i) {
      int row = m0 + wm * 64 + mi * 16 + 4 * g + i;
      int drow;
      if (RMODE == 1) drow = winmap_row(row);
      else if (RMODE == 2) drow = rowmap[row];
      else drow = row;
      #pragma unroll
      for (int ni = 0; ni < 2; ++ni) {
        int col = n0 + wn * 32 + ni * 16 + r16;
        float v = acc[mi][ni][i];
        if (BIAS) v += bias[col];
        if (DOGELU) v = gelu_f(v);
        if (OUTMODE == 0)      C[(size_t)drow * N + col] = v;
        else if (OUTMODE == 1) C[(size_t)drow * N + col] += v;
        else                   Ch[(size_t)drow * N + col] = f2b(v);
      }
    }
  }
}

// ---------------- f32 tiled GEMM (exact path: wq/wk/wv), 128x64 tile ----------------
template<bool BIAS>
__global__ __launch_bounds__(256)
void gemm128(const float* __restrict__ A, const float* __restrict__ W,
             const float* __restrict__ bias, float* __restrict__ C,
             int M, int N, int K, int lda) {
  __shared__ float As[32][128];
  __shared__ float Bs[32][64];
  int tid = threadIdx.x;
  int tx = tid & 15, ty = tid >> 4;
  int m0 = blockIdx.y * 128, n0 = blockIdx.x * 64;
  float acc[8][4] = {};
  for (int k0 = 0; k0 < K; k0 += 32) {
    #pragma unroll
    for (int q = 0; q < 4; ++q) {
      int i = tid * 4 + q;
      int r = i >> 3, c4 = (i & 7) << 2;
      float4 v = *(const float4*)(A + (size_t)(m0 + r) * lda + k0 + c4);
      As[c4 + 0][r] = v.x; As[c4 + 1][r] = v.y; As[c4 + 2][r] = v.z; As[c4 + 3][r] = v.w;
    }
    #pragma unroll
    for (int q = 0; q < 2; ++q) {
      int i = tid * 2 + q;
      int kc = i >> 4, nc = (i & 15) << 2;
      int col = n0 + nc;
      float4 v = make_float4(0.f, 0.f, 0.f, 0.f);
      if (col + 3 < N) {
        v = *(const float4*)(W + (size_t)(k0 + kc) * N + col);
      } else {
        float t[4] = {0.f, 0.f, 0.f, 0.f};
        #pragma unroll
        for (int e = 0; e < 4; ++e) if (col + e < N) t[e] = W[(size_t)(k0 + kc) * N + col + e];
        v = make_float4(t[0], t[1], t[2], t[3]);
      }
      *(float4*)&Bs[kc][nc] = v;
    }
    __syncthreads();
    #pragma unroll
    for (int kk = 0; kk < 32; ++kk) {
      float4 a0 = *(const float4*)&As[kk][ty * 8];
      float4 a1 = *(const float4*)&As[kk][ty * 8 + 4];
      float4 b  = *(const float4*)&Bs[kk][tx * 4];
      float av[8] = {a0.x, a0.y, a0.z, a0.w, a1.x, a1.y, a1.z, a1.w};
      #pragma unroll
      for (int ii = 0; ii < 8; ++ii) {
        acc[ii][0] += av[ii] * b.x; acc[ii][1] += av[ii] * b.y;
        acc[ii][2] += av[ii] * b.z; acc[ii][3] += av[ii] * b.w;
      }
    }
    __syncthreads();
  }
  #pragma unroll
  for (int ii = 0; ii < 8; ++ii) {
    int row = m0 + ty * 8 + ii;
    float* crow = C + (size_t)row * N;
    #pragma unroll
    for (int j = 0; j < 4; ++j) {
      int col = n0 + tx * 4 + j;
      if (col < N) {
        float v = acc[ii][j];
        if (BIAS) v += bias[col];
        crow[col] = v;
      }
    }
  }
}

// ---------------- merged flash attention (win + cat), bf16 qkv in, bf16 out ----------
__global__ __launch_bounds__(256)
void attn2_kernel(const short* __restrict__ qkvh, const int* __restrict__ sort_row,
                  const float* __restrict__ rpb_table, const float* __restrict__ ls_ptr,
                  short* __restrict__ obufW, short* __restrict__ obufC) {
  __shared__ float Ks[128][36];
  __shared__ float Vs[128][36];
  __shared__ float rpb_s[964];
  int b_ = blockIdx.x, head = blockIdx.y;
  bool IS_WIN = (blockIdx.z == 0);
  int tid = threadIdx.x;

  if (IS_WIN) {
    for (int idx = tid; idx < 961; idx += 256) rpb_s[idx] = rpb_table[idx * HEADS_ + head];
  }

  int gq = b_ * 256 + tid;
  int srcq = IS_WIN ? winmap_row(gq) : sort_row[gq];
  float qr[32];
  {
    const short* rowp = qkvh + (size_t)srcq * 576 + head * 32;
    #pragma unroll
    for (int q8 = 0; q8 < 4; ++q8) {
      s16x8 v = *(const s16x8*)(rowp + q8 * 8);
      #pragma unroll
      for (int e = 0; e < 8; ++e) qr[q8 * 8 + e] = b2f(v[e]);
    }
  }
  float scale = IS_WIN ? HD_SCALE : __expf(fminf(ls_ptr[0], LOG100));

  int win = b_ & 63;
  int wy = (win >> 3) << 4, wx = (win & 7) << 4;
  int py = tid >> 4, px = tid & 15;
  int ri = rgn(wy + py) * 3 + rgn(wx + px);

  float m = -3.4e38f, l = 0.f, acc[32];
  #pragma unroll
  for (int d = 0; d < 32; ++d) acc[d] = 0.f;

  int j = tid >> 1, half = tid & 1;
  for (int c0 = 0; c0 < 256; c0 += 128) {
    __syncthreads();
    {
      int src = IS_WIN ? winmap_row(b_ * 256 + c0 + j) : sort_row[b_ * 256 + c0 + j];
      const short* rowp = qkvh + (size_t)src * 576;
      const short* kp = rowp + 192 + head * 32 + half * 16;
      const short* vp = rowp + 384 + head * 32 + half * 16;
      s16x8 k0 = *(const s16x8*)(kp), k1 = *(const s16x8*)(kp + 8);
      s16x8 v0 = *(const s16x8*)(vp), v1 = *(const s16x8*)(vp + 8);
      float4 f;
      f = make_float4(b2f(k0[0]), b2f(k0[1]), b2f(k0[2]), b2f(k0[3])); *(float4*)&Ks[j][half*16]      = f;
      f = make_float4(b2f(k0[4]), b2f(k0[5]), b2f(k0[6]), b2f(k0[7])); *(float4*)&Ks[j][half*16 + 4]  = f;
      f = make_float4(b2f(k1[0]), b2f(k1[1]), b2f(k1[2]), b2f(k1[3])); *(float4*)&Ks[j][half*16 + 8]  = f;
      f = make_float4(b2f(k1[4]), b2f(k1[5]), b2f(k1[6]), b2f(k1[7])); *(float4*)&Ks[j][half*16 + 12] = f;
      f = make_float4(b2f(v0[0]), b2f(v0[1]), b2f(v0[2]), b2f(v0[3])); *(float4*)&Vs[j][half*16]      = f;
      f = make_float4(b2f(v0[4]), b2f(v0[5]), b2f(v0[6]), b2f(v0[7])); *(float4*)&Vs[j][half*16 + 4]  = f;
      f = make_float4(b2f(v1[0]), b2f(v1[1]), b2f(v1[2]), b2f(v1[3])); *(float4*)&Vs[j][half*16 + 8]  = f;
      f = make_float4(b2f(v1[4]), b2f(v1[5]), b2f(v1[6]), b2f(v1[7])); *(float4*)&Vs[j][half*16 + 12] = f;
    }
    __syncthreads();

    for (int j0 = 0; j0 < 128; j0 += 16) {
      float s[16];
      #pragma unroll
      for (int jj = 0; jj < 16; ++jj) {
        const float* kp = Ks[j0 + jj];
        float4 k0v = *(const float4*)(kp + 0),  k1v = *(const float4*)(kp + 4);
        float4 k2v = *(const float4*)(kp + 8),  k3v = *(const float4*)(kp + 12);
        float4 k4v = *(const float4*)(kp + 16), k5v = *(const float4*)(kp + 20);
        float4 k6v = *(const float4*)(kp + 24), k7v = *(const float4*)(kp + 28);
        float a = qr[0]*k0v.x + qr[1]*k0v.y + qr[2]*k0v.z + qr[3]*k0v.w
                + qr[4]*k1v.x + qr[5]*k1v.y + qr[6]*k1v.z + qr[7]*k1v.w
                + qr[8]*k2v.x + qr[9]*k2v.y + qr[10]*k2v.z + qr[11]*k2v.w
                + qr[12]*k3v.x + qr[13]*k3v.y + qr[14]*k3v.z + qr[15]*k3v.w
                + qr[16]*k4v.x + qr[17]*k4v.y + qr[18]*k4v.z + qr[19]*k4v.w
                + qr[20]*k5v.x + qr[21]*k5v.y + qr[22]*k5v.z + qr[23]*k5v.w
                + qr[24]*k6v.x + qr[25]*k6v.y + qr[26]*k6v.z + qr[27]*k6v.w
                + qr[28]*k7v.x + qr[29]*k7v.y + qr[30]*k7v.z + qr[31]*k7v.w;
        a *= scale;
        if (IS_WIN) {
          int jab = c0 + j0 + jj;
          int jy = jab >> 4, jx = jab & 15;
          int idx = (py - jy + 15) * 31 + (px - jx + 15);
          int rj = rgn(wy + jy) * 3 + rgn(wx + jx);
          a += rpb_s[idx] + (ri != rj ? -100.0f : 0.0f);
        }
        s[jj] = a;
      }
      float cm = s[0];
      #pragma unroll
      for (int jj = 1; jj < 16; ++jj) cm = fmaxf(cm, s[jj]);
      float mn = fmaxf(m, cm);
      float corr = __expf(m - mn);
      l *= corr;
      #pragma unroll
      for (int d = 0; d < 32; ++d) acc[d] *= corr;
      #pragma unroll
      for (int jj = 0; jj < 16; ++jj) {
        float p = __expf(s[jj] - mn);
        l += p;
        const float* vp = Vs[j0 + jj];
        #pragma unroll
        for (int d = 0; d < 32; ++d) acc[d] += p * vp[d];
      }
      m = mn;
    }
  }
  float inv = 1.0f / l;
  short* obuf = IS_WIN ? obufW : obufC;
  short* op = obuf + ((size_t)(b_ * 256 + tid)) * DIM_ + head * HD_;
  #pragma unroll
  for (int d8 = 0; d8 < 4; ++d8) {
    s16x8 v;
    #pragma unroll
    for (int e = 0; e < 8; ++e) v[e] = f2b(acc[d8 * 8 + e] * inv);
    *(s16x8*)(op + d8 * 8) = v;
  }
}

// ---------------- row L2-normalize, width 20 ----------------
__global__ __launch_bounds__(256)
void normrows20(float* __restrict__ p, int rows) {
  int r = blockIdx.x * 256 + threadIdx.x;
  if (r >= rows) return;
  float4* rp = (float4*)(p + (size_t)r * RD_);
  float4 v[5];
  float s = 0.f;
  #pragma unroll
  for (int e = 0; e < 5; ++e) {
    v[e] = rp[e];
    s += v[e].x * v[e].x + v[e].y * v[e].y + v[e].z * v[e].z + v[e].w * v[e].w;
  }
  float inv = 1.0f / fmaxf(sqrtf(s), 1e-12f);
  #pragma unroll
  for (int e = 0; e < 5; ++e) {
    v[e].x *= inv; v[e].y *= inv; v[e].z *= inv; v[e].w *= inv;
    rp[e] = v[e];
  }
}

// ---------------- sim: logits + argmax (pass1, exact f32) + probs (pass2) ----------------
// writes simNat f32 [n][t], simh bf16 [n][t], tk
__global__ __launch_bounds__(256)
void sim1_kernel(const float* __restrict__ qa, const float* __restrict__ ka,
                 const float* __restrict__ atd_scale, float* __restrict__ simNat,
                 short* __restrict__ simh, int* __restrict__ tk) {
  __shared__ float kas[NT_ * RD_];
  __shared__ float scl[NT_];
  int tid = threadIdx.x;
  int gi = blockIdx.x * 256 + tid;
  int b = blockIdx.x >> 6;
  for (int idx = tid; idx < NT_ * RD_; idx += 256) kas[idx] = ka[b * NT_ * RD_ + idx];
  for (int t = tid; t < NT_; t += 256)
    scl[t] = 1.0f + fminf(fmaxf(atd_scale[t], 0.f), 1.f) * LOGNT;
  __syncthreads();
  float q[20];
  const float4* qp = (const float4*)(qa + (size_t)gi * RD_);
  #pragma unroll
  for (int e = 0; e < 5; ++e) {
    float4 v = qp[e];
    q[e * 4] = v.x; q[e * 4 + 1] = v.y; q[e * 4 + 2] = v.z; q[e * 4 + 3] = v.w;
  }
  // pass 1: online max/denominator + argmax (bit-identical to prior rounds)
  float m = -3.4e38f, l = 0.f;
  int am = 0;
  for (int t = 0; t < NT_; ++t) {
    const float* kp = &kas[t * RD_];
    float d = 0.f;
    #pragma unroll
    for (int e = 0; e < 20; ++e) d += q[e] * kp[e];
    d *= scl[t];
    if (d > m) { l = l * __expf(m - d) + 1.0f; m = d; am = t; }
    else       { l += __expf(d - m); }
  }
  tk[gi] = am;
  float invl = 1.0f / l;
  // pass 2: recompute logits, emit probs
  float* so = simNat + (size_t)gi * NT_;
  short* sh = simh  + (size_t)gi * NT_;
  for (int t0 = 0; t0 < NT_; t0 += 8) {
    float p8[8];
    #pragma unroll
    for (int u = 0; u < 8; ++u) {
      int t = t0 + u;
      const float* kp = &kas[t * RD_];
      float d = 0.f;
      #pragma unroll
      for (int e = 0; e < 20; ++e) d += q[e] * kp[e];
      d *= scl[t];
      p8[u] = __expf(d - m) * invl;
    }
    *(float4*)(so + t0)     = make_float4(p8[0], p8[1], p8[2], p8[3]);
    *(float4*)(so + t0 + 4) = make_float4(p8[4], p8[5], p8[6], p8[7]);
    s16x8 h;
    #pragma unroll
    for (int u = 0; u < 8; ++u) h[u] = f2b(p8[u]);
    *(s16x8*)(sh + t0) = h;
  }
}

// ---------------- counting sort (stable) ----------------
__global__ __launch_bounds__(256)
void hist_kernel(const int* __restrict__ tk, int* __restrict__ chist) {
  __shared__ int h[NT_];
  int tid = threadIdx.x, ch = blockIdx.x, b = blockIdx.y;
  if (tid < NT_) h[tid] = 0;
  __syncthreads();
  int bin = tk[b * NN + ch * 256 + tid];
  atomicAdd(&h[bin], 1);
  __syncthreads();
  if (tid < NT_) chist[(b * 64 + ch) * NT_ + tid] = h[tid];
}

__global__ __launch_bounds__(128)
void offsets_kernel(const int* __restrict__ chist, int* __restrict__ offs) {
  int b = blockIdx.x, bin = threadIdx.x;
  int total = 0;
  for (int ch = 0; ch < 64; ++ch) total += chist[(b * 64 + ch) * NT_ + bin];
  __shared__ int sc[NT_];
  sc[bin] = total;
  __syncthreads();
  int base = 0;
  for (int i = 0; i < bin; ++i) base += sc[i];
  int run = base;
  for (int ch = 0; ch < 64; ++ch) {
    offs[(b * 64 + ch) * NT_ + bin] = run;
    run += chist[(b * 64 + ch) * NT_ + bin];
  }
}

__global__ __launch_bounds__(256)
void scatter_kernel(const int* __restrict__ tk, const int* __restrict__ offs,
                    int* __restrict__ sort_row) {
  __shared__ int bins[256];
  int tid = threadIdx.x, ch = blockIdx.x, b = blockIdx.y;
  int i = ch * 256 + tid;
  int bin = tk[b * NN + i];
  bins[tid] = bin;
  __syncthreads();
  int rank = 0;
  for (int jq = 0; jq < tid; ++jq) rank += (bins[jq] == bin) ? 1 : 0;
  int pos = offs[(b * 64 + ch) * NT_ + bin] + rank;
  sort_row[b * NN + pos] = b * NN + i;
}

// ---------------- depthwise 5x5 conv + bias + gelu (bf16 in/out) ----------------
__global__ __launch_bounds__(384)
void dwconv_kernel(const short* __restrict__ hdn, const float* __restrict__ wgt,
                   const float* __restrict__ bv, short* __restrict__ out) {
  int c = threadIdx.x;
  int xt = blockIdx.x, y = blockIdx.y, b = blockIdx.z;
  float wr[25];
  #pragma unroll
  for (int t = 0; t < 25; ++t) wr[t] = wgt[c * 25 + t];
  float bias = bv[c];
  int x0 = xt * 16;
  const short* base = hdn + (size_t)b * NN * HID_;
  float win[5][5];
  #pragma unroll
  for (int r = 0; r < 5; ++r) {
    int yy = y + r - 2;
    #pragma unroll
    for (int t = 0; t < 4; ++t) {
      int xx = x0 - 2 + t;
      win[r][t] = (yy >= 0 && yy < HH && xx >= 0 && xx < WW2)
                    ? b2f(base[((size_t)yy * WW2 + xx) * HID_ + c]) : 0.f;
    }
  }
  for (int x = x0; x < x0 + 16; ++x) {
    int xx = x + 2;
    #pragma unroll
    for (int r = 0; r < 5; ++r) {
      int yy = y + r - 2;
      win[r][4] = (yy >= 0 && yy < HH && xx < WW2)
                    ? b2f(base[((size_t)yy * WW2 + xx) * HID_ + c]) : 0.f;
    }
    float s = bias;
    #pragma unroll
    for (int r = 0; r < 5; ++r)
      #pragma unroll
      for (int t = 0; t < 5; ++t) s += win[r][t] * wr[r * 5 + t];
    s = gelu_f(s);
    out[((size_t)b * NN + (size_t)y * WW2 + x) * HID_ + c] = f2b(s);
    #pragma unroll
    for (int r = 0; r < 5; ++r) {
      win[r][0] = win[r][1]; win[r][1] = win[r][2];
      win[r][2] = win[r][3]; win[r][3] = win[r][4];
    }
  }
}

// ---------------- td stats over [n][t] layout: partial then final ----------------
__global__ __launch_bounds__(256)
void tdstats1(const float* __restrict__ simNat, float* __restrict__ tpart) {
  int b = blockIdx.y, seg = blockIdx.x;          // 16 segs of 1024 n
  int t = threadIdx.x & 127, half = threadIdx.x >> 7;
  float m = -3.4e38f, l = 0.f;
  const float* base = simNat + ((size_t)b * NN + seg * 1024 + half) * NT_ + t;
  for (int i = 0; i < 512; ++i) {
    float v = base[(size_t)i * 2 * NT_];
    if (v > m) { l = l * __expf(m - v) + 1.f; m = v; } else l += __expf(v - m);
  }
  __shared__ float sm[256], sl[256];
  sm[threadIdx.x] = m; sl[threadIdx.x] = l;
  __syncthreads();
  if (half == 0) {
    float m2 = sm[t + 128], l2 = sl[t + 128];
    float M = fmaxf(m, m2);
    float L = l * __expf(m - M) + l2 * __expf(m2 - M);
    tpart[((size_t)(b * 16 + seg) * 128 + t) * 2]     = M;
    tpart[((size_t)(b * 16 + seg) * 128 + t) * 2 + 1] = L;
  }
}

__global__ __launch_bounds__(256)
void tdstats2(const float* __restrict__ tpart, float* __restrict__ tmax,
              float* __restrict__ tden) {
  int bt = threadIdx.x;              // 256 = NB*NT
  int b = bt >> 7, t = bt & 127;
  float M = -3.4e38f, L = 0.f;
  for (int s = 0; s < 16; ++s) {
    float m = tpart[((size_t)(b * 16 + s) * 128 + t) * 2];
    float l = tpart[((size_t)(b * 16 + s) * 128 + t) * 2 + 1];
    float Mn = fmaxf(M, m);
    L = L * __expf(M - Mn) + l * __expf(m - Mn);
    M = Mn;
  }
  tmax[bt] = M; tden[bt] = L;
}

// ---------------- split-K: tdacc += mask_soft @ x  (simNat [n][t] layout) -------------
__global__ __launch_bounds__(192)
void tdgemm_kernel(const float* __restrict__ simNat, const float* __restrict__ tmax,
                   const float* __restrict__ tden, const float* __restrict__ xf,
                   float* __restrict__ tdacc) {
  int nch = blockIdx.x, tt4 = blockIdx.y, b = blockIdx.z;
  int t0 = tt4 * 32;
  int n0 = nch * 512;
  __shared__ float wtile[32][65];
  __shared__ float tmx[32], tdv[32];
  int tid = threadIdx.x;
  if (tid < 32) {
    tmx[tid] = tmax[b * NT_ + t0 + tid];
    tdv[tid] = tden[b * NT_ + t0 + tid];
  }
  __syncthreads();
  float acc[32] = {};
  for (int sub = 0; sub < 8; ++sub) {
    int nb = n0 + sub * 64;
    __syncthreads();
    for (int idx = tid; idx < 2048; idx += 192) {
      int nn = idx >> 5, tt = idx & 31;
      float raw = simNat[((size_t)(b * NN + nb + nn)) * NT_ + t0 + tt];
      wtile[tt][nn] = __expf(raw - tmx[tt]) / tdv[tt];
    }
    __syncthreads();
    for (int nn = 0; nn < 64; ++nn) {
      float xv = xf[((size_t)(b * NN + nb + nn)) * DIM_ + tid];
      #pragma unroll
      for (int trow = 0; trow < 32; ++trow) acc[trow] += wtile[trow][nn] * xv;
    }
  }
  #pragma unroll
  for (int trow = 0; trow < 32; ++trow)
    atomicAdd(&tdacc[((size_t)(b * NT_ + t0 + trow)) * DIM_ + tid], acc[trow]);
}

// ---------------- td blend + instance norm ----------------
__global__ __launch_bounds__(64)
void tdfinal_kernel(const float* __restrict__ td, const float* __restrict__ tdacc,
                    const float* __restrict__ sigma, const float* __restrict__ in3w,
                    const float* __restrict__ in3b, float* __restrict__ out) {
  int r = blockIdx.x;
  int lane = threadIdx.x;
  int t = r & (NT_ - 1);
  float sg = sigma[t];
  const float* ta = tdacc + (size_t)r * DIM_;
  const float* tp = td + (size_t)r * DIM_;
  float v0 = sg * tp[lane]       + (1.f - sg) * ta[lane];
  float v1 = sg * tp[lane + 64]  + (1.f - sg) * ta[lane + 64];
  float v2 = sg * tp[lane + 128] + (1.f - sg) * ta[lane + 128];
  float s = v0 + v1 + v2;
  #pragma unroll
  for (int m = 32; m; m >>= 1) s += __shfl_xor(s, m, 64);
  float mu = s * (1.0f / 192.0f);
  float d0 = v0 - mu, d1 = v1 - mu, d2 = v2 - mu;
  float q = d0 * d0 + d1 * d1 + d2 * d2;
  #pragma unroll
  for (int m = 32; m; m >>= 1) q += __shfl_xor(q, m, 64);
  float rs = rsqrtf(q * (1.0f / 192.0f) + 1e-5f);
  float w = in3w[t], bb = in3b[t];
  float* o = out + (size_t)ROWS * DIM_ + (size_t)r * DIM_;
  o[lane]       = d0 * rs * w + bb;
  o[lane + 64]  = d1 * rs * w + bb;
  o[lane + 128] = d2 * rs * w + bb;
}

// ---------------- host launch ----------------
extern "C" void kernel_launch(void* const* d_in, const int* in_sizes, int n_in,
                              void* d_out, int out_size, void* d_ws, size_t ws_size,
                              hipStream_t stream) {
  (void)in_sizes; (void)n_in; (void)out_size; (void)ws_size;
  const float* x          = (const float*)d_in[0];
  const float* td         = (const float*)d_in[1];
  const float* wqkv_w     = (const float*)d_in[3];
  const float* wqkv_b     = (const float*)d_in[4];
  const float* rpb_table  = (const float*)d_in[5];
  const float* win_proj_w = (const float*)d_in[6];
  const float* win_proj_b = (const float*)d_in[7];
  const float* wq_w       = (const float*)d_in[8];
  const float* wq_b       = (const float*)d_in[9];
  const float* wk_w       = (const float*)d_in[10];
  const float* wk_b       = (const float*)d_in[11];
  const float* wv_w       = (const float*)d_in[12];
  const float* wv_b       = (const float*)d_in[13];
  const float* atd_scale  = (const float*)d_in[14];
  const float* aca_proj_w = (const float*)d_in[15];
  const float* aca_proj_b = (const float*)d_in[16];
  const float* logit_scale= (const float*)d_in[17];
  const float* fc1_w      = (const float*)d_in[18];
  const float* fc1_b      = (const float*)d_in[19];
  const float* dw_w       = (const float*)d_in[20];
  const float* dw_b       = (const float*)d_in[21];
  const float* fc2_w      = (const float*)d_in[22];
  const float* fc2_b      = (const float*)d_in[23];
  const float* ln1_w      = (const float*)d_in[24];
  const float* ln1_b      = (const float*)d_in[25];
  const float* ln2_w      = (const float*)d_in[26];
  const float* ln2_b      = (const float*)d_in[27];
  const float* in3_w      = (const float*)d_in[28];
  const float* in3_b      = (const float*)d_in[29];
  const float* sigma      = (const float*)d_in[30];

  float* out = (float*)d_out;

  float* wsf = (float*)d_ws;
  size_t o = 0;
  float* xn     = wsf + o; o += (size_t)ROWS * DIM_;            // f32 LN out (wq path)
  short* xnh    = (short*)(wsf + o); o += (size_t)ROWS * DIM_ / 2;
  short* qkvh   = (short*)(wsf + o); o += (size_t)ROWS * 3 * DIM_ / 2;  // reused as hdnh
  short* obufWh = (short*)(wsf + o); o += (size_t)ROWS * DIM_ / 2;
  short* obufCh = (short*)(wsf + o); o += (size_t)ROWS * DIM_ / 2;
  float* simNat = wsf + o; o += (size_t)ROWS * NT_;
  short* simh   = (short*)(wsf + o); o += (size_t)ROWS * NT_ / 2;
  short* gridh  = (short*)(wsf + o); o += (size_t)ROWS * HID_ / 2;
  float* qa     = wsf + o; o += (size_t)ROWS * RD_;
  float* ka     = wsf + o; o += (size_t)NB * NT_ * RD_;
  float* va     = wsf + o; o += (size_t)NB * NT_ * DIM_;
  short* vat    = (short*)(wsf + o); o += (size_t)NB * NT_ * DIM_ / 2;
  float* tpart  = wsf + o; o += (size_t)NB * 16 * NT_ * 2;
  float* tmaxb  = wsf + o; o += NB * NT_;
  float* tdenb  = wsf + o; o += NB * NT_;
  float* tdacc  = wsf + o; o += (size_t)NB * NT_ * DIM_;
  int* tk       = (int*)(wsf + o); o += ROWS;
  int* chist    = (int*)(wsf + o); o += NB * 64 * NT_;
  int* coffs    = (int*)(wsf + o); o += NB * 64 * NT_;
  int* sort_row = (int*)(wsf + o); o += ROWS;
  short* wqkvT  = (short*)(wsf + o); o += (size_t)DIM_ * 576 / 2;
  short* winT   = (short*)(wsf + o); o += (size_t)DIM_ * DIM_ / 2;
  short* acaT   = (short*)(wsf + o); o += (size_t)DIM_ * DIM_ / 2;
  short* fc1T   = (short*)(wsf + o); o += (size_t)DIM_ * HID_ / 2;
  short* fc2T   = (short*)(wsf + o); o += (size_t)HID_ * DIM_ / 2;
  short* hdnh   = qkvh;   // fc1 out reuses dead qkv region

  // 0. weight transpose+cast (independent)
  transcast<<<dim3(576/32, 192/32), 256, 0, stream>>>(wqkv_w, wqkvT, 192, 576);
  transcast<<<dim3(192/32, 192/32), 256, 0, stream>>>(win_proj_w, winT, 192, 192);
  transcast<<<dim3(192/32, 192/32), 256, 0, stream>>>(aca_proj_w, acaT, 192, 192);
  transcast<<<dim3(384/32, 192/32), 256, 0, stream>>>(fc1_w, fc1T, 192, 384);
  transcast<<<dim3(192/32, 384/32), 256, 0, stream>>>(fc2_w, fc2T, 384, 192);
  // 1. accumulator = shortcut
  hipMemcpyAsync(out, x, (size_t)ROWS * DIM_ * sizeof(float),
                 hipMemcpyDeviceToDevice, stream);
  // 2. xn = LN1(x) (f32 + bf16)
  ln_kernel<<<ROWS / 4, 256, 0, stream>>>(x, ln1_w, ln1_b, xn, xnh, ROWS);
  // 3. qkvh = xnh @ wqkvT (bf16 out)
  gemm_mfma<6, true, false, 0, 2><<<dim3(9, ROWS/128), 256, 0, stream>>>(
      xnh, wqkvT, wqkv_b, nullptr, qkvh, 576, nullptr);
  // 4. exact f32 path: qa/ka/va
  gemm128<true><<<dim3(1, ROWS/128), 256, 0, stream>>>(xn, wq_w, wq_b, qa, ROWS, 20, 192, 192);
  gemm128<true><<<dim3(1, 2), 256, 0, stream>>>(td, wk_w, wk_b, ka, NB*NT_, 20, 192, 192);
  gemm128<true><<<dim3(3, 2), 256, 0, stream>>>(td, wv_w, wv_b, va, NB*NT_, 192, 192, 192);
  normrows20<<<ROWS / 256, 256, 0, stream>>>(qa, ROWS);
  normrows20<<<1, 256, 0, stream>>>(ka, NB * NT_);
  // va -> vat bf16 transposed (per batch)
  transcast<<<dim3(192/32, 128/32), 256, 0, stream>>>(va, vat, 128, 192);
  transcast<<<dim3(192/32, 128/32), 256, 0, stream>>>(va + (size_t)NT_*DIM_, vat + (size_t)DIM_*NT_, 128, 192);
  // 5. sim probs + argmax (f32 exact)
  sim1_kernel<<<ROWS / 256, 256, 0, stream>>>(qa, ka, atd_scale, simNat, simh, tk);
  // 6. stable counting sort by tk
  hist_kernel<<<dim3(64, NB), 256, 0, stream>>>(tk, chist);
  offsets_kernel<<<NB, 128, 0, stream>>>(chist, coffs);
  scatter_kernel<<<dim3(64, NB), 256, 0, stream>>>(tk, coffs, sort_row);
  // 7. merged attention (bf16 I/O)
  attn2_kernel<<<dim3(128, 6, 2), 256, 0, stream>>>(
      qkvh, sort_row, rpb_table, logit_scale, obufWh, obufCh);
  // 8. projections / x_atd, scatter-add into accumulator (MFMA)
  gemm_mfma<6, true, false, 1, 1><<<dim3(3, ROWS/128), 256, 0, stream>>>(
      obufWh, winT, win_proj_b, out, nullptr, 192, nullptr);
  gemm_mfma<6, true, false, 2, 1><<<dim3(3, ROWS/128), 256, 0, stream>>>(
      obufCh, acaT, aca_proj_b, out, nullptr, 192, sort_row);
  for (int b = 0; b < NB; ++b) {
    gemm_mfma<4, false, false, 0, 1><<<dim3(3, NN/128), 256, 0, stream>>>(
        simh + (size_t)b * NN * NT_, vat + (size_t)b * DIM_ * NT_, nullptr,
        out + (size_t)b * NN * DIM_, nullptr, 192, nullptr);
  }
  // 9. xn2 = LN2(x)
  ln_kernel<<<ROWS / 4, 256, 0, stream>>>(out, ln2_w, ln2_b, xn, xnh, ROWS);
  // 10. hdnh = gelu(xn2h @ fc1T) (bf16 out)
  gemm_mfma<6, true, true, 0, 2><<<dim3(6, ROWS/128), 256, 0, stream>>>(
      xnh, fc1T, fc1_b, nullptr, hdnh, 384, nullptr);
  // 11. depthwise conv 5x5 + bias + gelu (bf16)
  dwconv_kernel<<<dim3(8, 128, NB), 384, 0, stream>>>(hdnh, dw_w, dw_b, gridh);
  // 12. x += gridh @ fc2T
  gemm_mfma<12, true, false, 0, 1><<<dim3(3, ROWS/128), 256, 0, stream>>>(
      gridh, fc2T, fc2_b, out, nullptr, 192, nullptr);
  // 13-14. td refinement
  tdstats1<<<dim3(16, NB), 256, 0, stream>>>(simNat, tpart);
  tdstats2<<<1, 256, 0, stream>>>(tpart, tmaxb, tdenb);
  hipMemsetAsync(tdacc, 0, (size_t)NB * NT_ * DIM_ * sizeof(float), stream);
  tdgemm_kernel<<<dim3(32, 4, NB), 192, 0, stream>>>(simNat, tmaxb, tdenb, out, tdacc);
  // 15. blend with sigma + instance norm -> out tail
  tdfinal_kernel<<<NB * NT_, 64, 0, stream>>>(td, tdacc, sigma, in3_w, in3_b, out);
}